// Round 1
// baseline (3054.969 us; speedup 1.0000x reference)
//
#include <hip/hip_runtime.h>

#define BWIN 256
#define NTOK 343
#define CDIM 192
#define NH   6
#define HD   32
#define QKVF 576                 // 3*CDIM
#define NROWS (BWIN * NTOK)      // 87808
#define QT   12                  // query tile for attention

// ------------------------------------------------------------------ sentinel
// Launched only if ws_size is too small for the qkv scratch: absmax ~1e6
// becomes an unambiguous "workspace too small" signal for the next round.
__global__ void ws_too_small_sentinel(float* out) { out[0] = 1.0e6f; }

// ------------------------------------------------------------------ QKV GEMM
// qkv[m][f] = sum_k x[m][k] * w[f][k] + b[f];  f<192 (q) pre-scaled by 1/sqrt(32).
// 64x64 tile, 4x4 micro-tile, K=16 chunks staged transposed in LDS so the
// inner loop is 2x ds_read_b128 + 16 independent FMAs.
__global__ __launch_bounds__(256) void qkv_gemm(
    const float* __restrict__ x, const float* __restrict__ w,
    const float* __restrict__ b, float* __restrict__ qkv)
{
    __shared__ float aT[16][68];   // [k][m], pad 68 keeps float4 16B-aligned
    __shared__ float bT[16][68];   // [k][f]
    const int m0 = blockIdx.x * 64;
    const int f0 = blockIdx.y * 64;
    const int tid = threadIdx.x;
    const int tx = tid & 15, ty = tid >> 4;
    float acc[4][4] = {};
    for (int kc = 0; kc < CDIM; kc += 16) {
        const int sr = tid >> 2;            // 0..63 row
        const int sk = (tid & 3) << 2;      // 0,4,8,12
        const float4 av = *(const float4*)(x + (size_t)(m0 + sr) * CDIM + kc + sk);
        const float4 bv = *(const float4*)(w + (size_t)(f0 + sr) * CDIM + kc + sk);
        aT[sk + 0][sr] = av.x; aT[sk + 1][sr] = av.y;
        aT[sk + 2][sr] = av.z; aT[sk + 3][sr] = av.w;
        bT[sk + 0][sr] = bv.x; bT[sk + 1][sr] = bv.y;
        bT[sk + 2][sr] = bv.z; bT[sk + 3][sr] = bv.w;
        __syncthreads();
        #pragma unroll
        for (int k = 0; k < 16; ++k) {
            const float4 a4 = *(const float4*)&aT[k][ty << 2];
            const float4 b4 = *(const float4*)&bT[k][tx << 2];
            acc[0][0] += a4.x * b4.x; acc[0][1] += a4.x * b4.y;
            acc[0][2] += a4.x * b4.z; acc[0][3] += a4.x * b4.w;
            acc[1][0] += a4.y * b4.x; acc[1][1] += a4.y * b4.y;
            acc[1][2] += a4.y * b4.z; acc[1][3] += a4.y * b4.w;
            acc[2][0] += a4.z * b4.x; acc[2][1] += a4.z * b4.y;
            acc[2][2] += a4.z * b4.z; acc[2][3] += a4.z * b4.w;
            acc[3][0] += a4.w * b4.x; acc[3][1] += a4.w * b4.y;
            acc[3][2] += a4.w * b4.z; acc[3][3] += a4.w * b4.w;
        }
        __syncthreads();
    }
    const float scale = (f0 < CDIM) ? 0.17677669529663687f : 1.0f; // 1/sqrt(32)
    const int fc = f0 + (tx << 2);
    const float4 bq = *(const float4*)(b + fc);
    #pragma unroll
    for (int r = 0; r < 4; ++r) {
        float4 o;
        o.x = (acc[r][0] + bq.x) * scale;
        o.y = (acc[r][1] + bq.y) * scale;
        o.z = (acc[r][2] + bq.z) * scale;
        o.w = (acc[r][3] + bq.w) * scale;
        *(float4*)(qkv + (size_t)(m0 + (ty << 2) + r) * QKVF + fc) = o;
    }
}

// ------------------------------------------------------------------ attention
// One block per (window b, head h). LDS = 61.9 KB (<= 64 KB/WG to be safe).
// K^T staged once; per 12-query tile: scores (+inline rel-pos bias gather),
// wave-shuffle softmax, PV with V streamed from global (coalesced, L2-hot).
__global__ __launch_bounds__(256) void attn_kernel(
    const float* __restrict__ qkv,        // [NROWS][576] (q pre-scaled)
    const float* __restrict__ btab,       // [2197][6]
    const int*   __restrict__ ridx,       // [343][343]
    float* __restrict__ out)              // [NROWS][192] attn output (pre-proj)
{
    __shared__ float kT[HD][NTOK];        // 43904 B, [d][j]: j-consecutive reads
    __shared__ float S [QT][NTOK];        // 16464 B scores->probs
    __shared__ float qo[QT][HD];          // 1536 B: q tile, reused as out accum
    __shared__ float inv_l[QT];
    const int b = blockIdx.x;
    const int h = blockIdx.y;
    const int tid = threadIdx.x;
    const size_t rowbase = (size_t)b * NTOK;

    for (int idx = tid; idx < NTOK * HD; idx += 256) {
        const int j = idx >> 5, d = idx & 31;
        kT[d][j] = qkv[(rowbase + j) * QKVF + CDIM + h * HD + d];
    }
    __syncthreads();

    for (int q0 = 0; q0 < NTOK; q0 += QT) {
        const int qcnt = (NTOK - q0 < QT) ? (NTOK - q0) : QT;
        // stage q tile (q already scaled)
        for (int idx = tid; idx < qcnt * HD; idx += 256) {
            const int qi = idx >> 5, d = idx & 31;
            qo[qi][d] = qkv[(rowbase + q0 + qi) * QKVF + h * HD + d];
        }
        __syncthreads();
        // scores: S[qi][j] = q.k + bias
        for (int idx = tid; idx < qcnt * NTOK; idx += 256) {
            const int qi = idx / NTOK;
            const int j  = idx - qi * NTOK;
            const int r  = ridx[(q0 + qi) * NTOK + j];
            float s0 = btab[r * NH + h], s1 = 0.f, s2 = 0.f, s3 = 0.f;
            #pragma unroll
            for (int d4 = 0; d4 < 8; ++d4) {
                const float4 qv = *(const float4*)&qo[qi][d4 << 2];
                s0 += qv.x * kT[(d4 << 2) + 0][j];
                s1 += qv.y * kT[(d4 << 2) + 1][j];
                s2 += qv.z * kT[(d4 << 2) + 2][j];
                s3 += qv.w * kT[(d4 << 2) + 3][j];
            }
            S[qi][j] = (s0 + s1) + (s2 + s3);
        }
        __syncthreads();
        // softmax: wave per row (3 rows/wave)
        {
            const int lane = tid & 63;
            const int wv = tid >> 6;
            for (int qi = wv; qi < qcnt; qi += 4) {
                float m = -3.0e38f;
                for (int j = lane; j < NTOK; j += 64) m = fmaxf(m, S[qi][j]);
                #pragma unroll
                for (int off = 32; off; off >>= 1) m = fmaxf(m, __shfl_xor(m, off));
                float l = 0.f;
                for (int j = lane; j < NTOK; j += 64) {
                    const float p = __expf(S[qi][j] - m);
                    S[qi][j] = p;
                    l += p;
                }
                #pragma unroll
                for (int off = 32; off; off >>= 1) l += __shfl_xor(l, off);
                if (lane == 0) inv_l[qi] = 1.0f / l;
            }
        }
        __syncthreads();
        // zero output accumulator (reuses qo)
        for (int idx = tid; idx < QT * HD; idx += 256) ((float*)qo)[idx] = 0.f;
        __syncthreads();
        // PV: 8 j-groups x 32 d; 12 reg accumulators each, LDS atomic combine.
        {
            const int d = tid & 31;
            const int g = tid >> 5;                 // 0..7
            float part[QT];
            #pragma unroll
            for (int qi = 0; qi < QT; ++qi) part[qi] = 0.f;
            for (int j = g; j < NTOK; j += 8) {
                const float vj = qkv[(rowbase + j) * QKVF + 2 * CDIM + h * HD + d];
                #pragma unroll
                for (int qi = 0; qi < QT; ++qi)     // stale rows (qi>=qcnt) are
                    part[qi] += S[qi][j] * vj;      // finite old probs; discarded
            }
            #pragma unroll
            for (int qi = 0; qi < QT; ++qi) atomicAdd(&qo[qi][d], part[qi]);
        }
        __syncthreads();
        // write attention output [b][n][h*32+d]
        for (int idx = tid; idx < qcnt * HD; idx += 256) {
            const int qi = idx >> 5, d = idx & 31;
            out[(rowbase + q0 + qi) * CDIM + h * HD + d] = qo[qi][d] * inv_l[qi];
        }
        __syncthreads();   // qo/S reused next tile
    }
}

// ------------------------------------------------------------------ proj GEMM (in-place on d_out)
// Each block owns 64 disjoint rows and the FULL 192-col range; all reads of its
// rows happen during K-loop staging, writes only in the epilogue -> race-free.
__global__ __launch_bounds__(256) void proj_gemm_inplace(
    float* __restrict__ io, const float* __restrict__ w, const float* __restrict__ b)
{
    __shared__ float aT[16][68];    // [k][m]
    __shared__ float bT[16][196];   // [k][f], pad keeps float4 alignment
    const int m0 = blockIdx.x * 64;
    const int tid = threadIdx.x;
    const int tx = tid & 15, ty = tid >> 4;
    float acc[4][12] = {};
    for (int kc = 0; kc < CDIM; kc += 16) {
        {
            const int sr = tid >> 2;
            const int sk = (tid & 3) << 2;
            const float4 v = *(const float4*)(io + (size_t)(m0 + sr) * CDIM + kc + sk);
            aT[sk + 0][sr] = v.x; aT[sk + 1][sr] = v.y;
            aT[sk + 2][sr] = v.z; aT[sk + 3][sr] = v.w;
        }
        #pragma unroll
        for (int p = 0; p < 3; ++p) {
            const int u = tid + 256 * p;            // 768 float4 units
            const int f = u >> 2;
            const int sk = (u & 3) << 2;
            const float4 v = *(const float4*)(w + (size_t)f * CDIM + kc + sk);
            bT[sk + 0][f] = v.x; bT[sk + 1][f] = v.y;
            bT[sk + 2][f] = v.z; bT[sk + 3][f] = v.w;
        }
        __syncthreads();
        #pragma unroll
        for (int k = 0; k < 16; ++k) {
            const float4 a4 = *(const float4*)&aT[k][ty << 2];
            #pragma unroll
            for (int c4 = 0; c4 < 3; ++c4) {
                const float4 b4 = *(const float4*)&bT[k][(tx << 2) + (c4 << 6)];
                const int c = c4 << 2;
                acc[0][c + 0] += a4.x * b4.x; acc[0][c + 1] += a4.x * b4.y;
                acc[0][c + 2] += a4.x * b4.z; acc[0][c + 3] += a4.x * b4.w;
                acc[1][c + 0] += a4.y * b4.x; acc[1][c + 1] += a4.y * b4.y;
                acc[1][c + 2] += a4.y * b4.z; acc[1][c + 3] += a4.y * b4.w;
                acc[2][c + 0] += a4.z * b4.x; acc[2][c + 1] += a4.z * b4.y;
                acc[2][c + 2] += a4.z * b4.z; acc[2][c + 3] += a4.z * b4.w;
                acc[3][c + 0] += a4.w * b4.x; acc[3][c + 1] += a4.w * b4.y;
                acc[3][c + 2] += a4.w * b4.z; acc[3][c + 3] += a4.w * b4.w;
            }
        }
        __syncthreads();
    }
    #pragma unroll
    for (int c4 = 0; c4 < 3; ++c4) {
        const int fc = (tx << 2) + (c4 << 6);
        const float4 bp = *(const float4*)(b + fc);
        #pragma unroll
        for (int r = 0; r < 4; ++r) {
            float4 o;
            o.x = acc[r][(c4 << 2) + 0] + bp.x;
            o.y = acc[r][(c4 << 2) + 1] + bp.y;
            o.z = acc[r][(c4 << 2) + 2] + bp.z;
            o.w = acc[r][(c4 << 2) + 3] + bp.w;
            *(float4*)(io + (size_t)(m0 + (ty << 2) + r) * CDIM + fc) = o;
        }
    }
}

// ------------------------------------------------------------------ launch
extern "C" void kernel_launch(void* const* d_in, const int* in_sizes, int n_in,
                              void* d_out, int out_size, void* d_ws, size_t ws_size,
                              hipStream_t stream) {
    const float* x     = (const float*)d_in[0];
    const float* wqkv  = (const float*)d_in[1];
    const float* bqkv  = (const float*)d_in[2];
    const float* wproj = (const float*)d_in[3];
    const float* bproj = (const float*)d_in[4];
    const float* btab  = (const float*)d_in[5];
    const int*   ridx  = (const int*)d_in[6];
    // d_in[7] = is_global (0 -> local window path; only path implemented)
    float* out = (float*)d_out;
    float* qkv = (float*)d_ws;

    const size_t need = (size_t)NROWS * QKVF * sizeof(float);   // 193.5 MiB
    if (ws_size < need) {
        hipLaunchKernelGGL(ws_too_small_sentinel, dim3(1), dim3(1), 0, stream, out);
        return;
    }
    hipLaunchKernelGGL(qkv_gemm, dim3(NROWS / 64, QKVF / 64), dim3(256), 0, stream,
                       x, wqkv, bqkv, qkv);
    hipLaunchKernelGGL(attn_kernel, dim3(BWIN, NH), dim3(256), 0, stream,
                       qkv, btab, ridx, out);
    hipLaunchKernelGGL(proj_gemm_inplace, dim3(NROWS / 64), dim3(256), 0, stream,
                       out, wproj, bproj);
}

// Round 2
// 1177.399 us; speedup vs baseline: 2.5947x; 2.5947x over previous
//
#include <hip/hip_runtime.h>

#define BWIN 256
#define NTOK 343
#define CDIM 192
#define NH   6
#define HD   32
#define QKVF 576                 // 3*CDIM
#define NROWS (BWIN * NTOK)      // 87808
#define QTL  64                  // query tile
#define JTL  64                  // key tile
#define NQC  6                   // ceil(343/64)
#define NJT  6

// ------------------------------------------------------------------ sentinel
__global__ void ws_too_small_sentinel(float* out) { out[0] = 1.0e6f; }

// ------------------------------------------------------------------ QKV GEMM (unchanged from R1)
__global__ __launch_bounds__(256) void qkv_gemm(
    const float* __restrict__ x, const float* __restrict__ w,
    const float* __restrict__ b, float* __restrict__ qkv)
{
    __shared__ float aT[16][68];
    __shared__ float bT[16][68];
    const int m0 = blockIdx.x * 64;
    const int f0 = blockIdx.y * 64;
    const int tid = threadIdx.x;
    const int tx = tid & 15, ty = tid >> 4;
    float acc[4][4] = {};
    for (int kc = 0; kc < CDIM; kc += 16) {
        const int sr = tid >> 2;
        const int sk = (tid & 3) << 2;
        const float4 av = *(const float4*)(x + (size_t)(m0 + sr) * CDIM + kc + sk);
        const float4 bv = *(const float4*)(w + (size_t)(f0 + sr) * CDIM + kc + sk);
        aT[sk + 0][sr] = av.x; aT[sk + 1][sr] = av.y;
        aT[sk + 2][sr] = av.z; aT[sk + 3][sr] = av.w;
        bT[sk + 0][sr] = bv.x; bT[sk + 1][sr] = bv.y;
        bT[sk + 2][sr] = bv.z; bT[sk + 3][sr] = bv.w;
        __syncthreads();
        #pragma unroll
        for (int k = 0; k < 16; ++k) {
            const float4 a4 = *(const float4*)&aT[k][ty << 2];
            const float4 b4 = *(const float4*)&bT[k][tx << 2];
            acc[0][0] += a4.x * b4.x; acc[0][1] += a4.x * b4.y;
            acc[0][2] += a4.x * b4.z; acc[0][3] += a4.x * b4.w;
            acc[1][0] += a4.y * b4.x; acc[1][1] += a4.y * b4.y;
            acc[1][2] += a4.y * b4.z; acc[1][3] += a4.y * b4.w;
            acc[2][0] += a4.z * b4.x; acc[2][1] += a4.z * b4.y;
            acc[2][2] += a4.z * b4.z; acc[2][3] += a4.z * b4.w;
            acc[3][0] += a4.w * b4.x; acc[3][1] += a4.w * b4.y;
            acc[3][2] += a4.w * b4.z; acc[3][3] += a4.w * b4.w;
        }
        __syncthreads();
    }
    const float scale = (f0 < CDIM) ? 0.17677669529663687f : 1.0f; // 1/sqrt(32) on q
    const int fc = f0 + (tx << 2);
    const float4 bq = *(const float4*)(b + fc);
    #pragma unroll
    for (int r = 0; r < 4; ++r) {
        float4 o;
        o.x = (acc[r][0] + bq.x) * scale;
        o.y = (acc[r][1] + bq.y) * scale;
        o.z = (acc[r][2] + bq.z) * scale;
        o.w = (acc[r][3] + bq.w) * scale;
        *(float4*)(qkv + (size_t)(m0 + (ty << 2) + r) * QKVF + fc) = o;
    }
}

// ------------------------------------------------------------------ flash attention (fp32, register-tiled)
// Grid (qchunk, head, window). Block 256 = 16(tq: 4 q-rows) x 16(tj: 4 j / 2 d).
// Online softmax state (m, l, alpha) lives in registers, replicated across the
// 16 tj lanes of a tq group (shfl_xor over lane bits 0..3). PV reuses the same
// tq->qi ownership, so the alpha rescale of O never touches LDS. No atomics.
__global__ __launch_bounds__(256) void attn_flash(
    const float* __restrict__ qkv,        // [NROWS][576], q pre-scaled
    const float* __restrict__ btab,       // [2197][6]
    const int*   __restrict__ ridx,       // [343][343]
    float* __restrict__ out)              // [NROWS][192]
{
    __shared__ float qT[HD][68];          // [k][m]  8704 B
    __shared__ float kT[HD][68];          // [k][j]  8704 B
    __shared__ float Vs[JTL][HD];         // [j][d]  8192 B
    __shared__ float Ss[JTL][68];         // [j][qi] 17408 B
    __shared__ float bt[2197];            // bias col for this head, 8788 B
    const int qc  = blockIdx.x;
    const int h   = blockIdx.y;
    const int b   = blockIdx.z;
    const int tid = threadIdx.x;
    const int tq  = tid >> 4;             // 0..15
    const int tj  = tid & 15;             // 0..15 (lane bits 0..3)
    const int q0  = qc * QTL;
    const size_t rowbase = (size_t)b * NTOK;

    for (int r = tid; r < 2197; r += 256) bt[r] = btab[r * NH + h];

    for (int u = tid; u < 512; u += 256) {           // stage qT transposed
        const int m = u >> 3, c4 = (u & 7) << 2;
        float4 v = make_float4(0.f, 0.f, 0.f, 0.f);
        if (q0 + m < NTOK)
            v = *(const float4*)(qkv + (rowbase + q0 + m) * QKVF + h * HD + c4);
        qT[c4 + 0][m] = v.x; qT[c4 + 1][m] = v.y;
        qT[c4 + 2][m] = v.z; qT[c4 + 3][m] = v.w;
    }

    float o0[4], o1[4], mr[4], lr[4];
    #pragma unroll
    for (int i = 0; i < 4; ++i) { o0[i] = 0.f; o1[i] = 0.f; mr[i] = -1.0e30f; lr[i] = 0.f; }

    for (int jt = 0; jt < NJT; ++jt) {
        const int j0 = jt * JTL;
        __syncthreads();   // A: prev PV (Ss/Vs reads) and prev scores (kT) done
        for (int u = tid; u < 512; u += 256) {       // stage kT (transposed) + Vs
            const int j = u >> 3, c4 = (u & 7) << 2;
            float4 kv = make_float4(0.f,0.f,0.f,0.f), vv = make_float4(0.f,0.f,0.f,0.f);
            if (j0 + j < NTOK) {
                const float* row = qkv + (rowbase + j0 + j) * QKVF + h * HD;
                kv = *(const float4*)(row + CDIM);
                vv = *(const float4*)(row + 2 * CDIM);
                kv = *(const float4*)(row + CDIM + c4);
                vv = *(const float4*)(row + 2 * CDIM + c4);
            }
            kT[c4 + 0][j] = kv.x; kT[c4 + 1][j] = kv.y;
            kT[c4 + 2][j] = kv.z; kT[c4 + 3][j] = kv.w;
            *(float4*)&Vs[j][c4] = vv;
        }
        __syncthreads();   // B: tiles staged

        // ---- scores (init = rel-pos bias; -1e30 for j >= NTOK)
        float s[4][4];
        #pragma unroll
        for (int i = 0; i < 4; ++i) {
            const int rq = min(q0 + (tq << 2) + i, NTOK - 1);
            const int cb = rq * NTOK + j0 + (tj << 2);
            #pragma unroll
            for (int jj = 0; jj < 4; ++jj) {
                const int jg = j0 + (tj << 2) + jj;
                s[i][jj] = (jg < NTOK) ? bt[ridx[cb + jj]] : -1.0e30f;
            }
        }
        #pragma unroll
        for (int k = 0; k < HD; ++k) {
            const float4 a  = *(const float4*)&qT[k][tq << 2];
            const float4 kk = *(const float4*)&kT[k][tj << 2];
            s[0][0] += a.x * kk.x; s[0][1] += a.x * kk.y; s[0][2] += a.x * kk.z; s[0][3] += a.x * kk.w;
            s[1][0] += a.y * kk.x; s[1][1] += a.y * kk.y; s[1][2] += a.y * kk.z; s[1][3] += a.y * kk.w;
            s[2][0] += a.z * kk.x; s[2][1] += a.z * kk.y; s[2][2] += a.z * kk.z; s[2][3] += a.z * kk.w;
            s[3][0] += a.w * kk.x; s[3][1] += a.w * kk.y; s[3][2] += a.w * kk.z; s[3][3] += a.w * kk.w;
        }

        // ---- online softmax (registers + shuffles only)
        #pragma unroll
        for (int i = 0; i < 4; ++i) {
            float tmx = fmaxf(fmaxf(s[i][0], s[i][1]), fmaxf(s[i][2], s[i][3]));
            tmx = fmaxf(tmx, __shfl_xor(tmx, 1));
            tmx = fmaxf(tmx, __shfl_xor(tmx, 2));
            tmx = fmaxf(tmx, __shfl_xor(tmx, 4));
            tmx = fmaxf(tmx, __shfl_xor(tmx, 8));
            const float nm    = fmaxf(mr[i], tmx);
            const float alpha = __expf(mr[i] - nm);
            mr[i] = nm;
            float rs = 0.f;
            #pragma unroll
            for (int jj = 0; jj < 4; ++jj) { s[i][jj] = __expf(s[i][jj] - nm); rs += s[i][jj]; }
            rs += __shfl_xor(rs, 1); rs += __shfl_xor(rs, 2);
            rs += __shfl_xor(rs, 4); rs += __shfl_xor(rs, 8);
            lr[i] = lr[i] * alpha + rs;
            o0[i] *= alpha; o1[i] *= alpha;
        }

        // ---- P -> LDS (transposed to [j][qi]) for PV
        #pragma unroll
        for (int jj = 0; jj < 4; ++jj)
            *(float4*)&Ss[(tj << 2) + jj][tq << 2] =
                make_float4(s[0][jj], s[1][jj], s[2][jj], s[3][jj]);
        __syncthreads();   // C

        // ---- PV: micro-tile 4 qi x 2 d; padded rows have P=0 and V=0
        #pragma unroll 4
        for (int j = 0; j < JTL; ++j) {
            const float4 a = *(const float4*)&Ss[j][tq << 2];
            const float2 v = *(const float2*)&Vs[j][tj << 1];
            o0[0] += a.x * v.x; o1[0] += a.x * v.y;
            o0[1] += a.y * v.x; o1[1] += a.y * v.y;
            o0[2] += a.z * v.x; o1[2] += a.z * v.y;
            o0[3] += a.w * v.x; o1[3] += a.w * v.y;
        }
    }

    #pragma unroll
    for (int i = 0; i < 4; ++i) {
        const int qg = q0 + (tq << 2) + i;
        if (qg < NTOK) {
            const float inv = 1.0f / lr[i];
            *(float2*)(out + (rowbase + qg) * CDIM + h * HD + (tj << 1)) =
                make_float2(o0[i] * inv, o1[i] * inv);
        }
    }
}

// ------------------------------------------------------------------ proj GEMM (in-place, unchanged from R1)
__global__ __launch_bounds__(256) void proj_gemm_inplace(
    float* __restrict__ io, const float* __restrict__ w, const float* __restrict__ b)
{
    __shared__ float aT[16][68];
    __shared__ float bT[16][196];
    const int m0 = blockIdx.x * 64;
    const int tid = threadIdx.x;
    const int tx = tid & 15, ty = tid >> 4;
    float acc[4][12] = {};
    for (int kc = 0; kc < CDIM; kc += 16) {
        {
            const int sr = tid >> 2;
            const int sk = (tid & 3) << 2;
            const float4 v = *(const float4*)(io + (size_t)(m0 + sr) * CDIM + kc + sk);
            aT[sk + 0][sr] = v.x; aT[sk + 1][sr] = v.y;
            aT[sk + 2][sr] = v.z; aT[sk + 3][sr] = v.w;
        }
        #pragma unroll
        for (int p = 0; p < 3; ++p) {
            const int u = tid + 256 * p;
            const int f = u >> 2;
            const int sk = (u & 3) << 2;
            const float4 v = *(const float4*)(w + (size_t)f * CDIM + kc + sk);
            bT[sk + 0][f] = v.x; bT[sk + 1][f] = v.y;
            bT[sk + 2][f] = v.z; bT[sk + 3][f] = v.w;
        }
        __syncthreads();
        #pragma unroll
        for (int k = 0; k < 16; ++k) {
            const float4 a4 = *(const float4*)&aT[k][ty << 2];
            #pragma unroll
            for (int c4 = 0; c4 < 3; ++c4) {
                const float4 b4 = *(const float4*)&bT[k][(tx << 2) + (c4 << 6)];
                const int c = c4 << 2;
                acc[0][c + 0] += a4.x * b4.x; acc[0][c + 1] += a4.x * b4.y;
                acc[0][c + 2] += a4.x * b4.z; acc[0][c + 3] += a4.x * b4.w;
                acc[1][c + 0] += a4.y * b4.x; acc[1][c + 1] += a4.y * b4.y;
                acc[1][c + 2] += a4.y * b4.z; acc[1][c + 3] += a4.y * b4.w;
                acc[2][c + 0] += a4.z * b4.x; acc[2][c + 1] += a4.z * b4.y;
                acc[2][c + 2] += a4.z * b4.z; acc[2][c + 3] += a4.z * b4.w;
                acc[3][c + 0] += a4.w * b4.x; acc[3][c + 1] += a4.w * b4.y;
                acc[3][c + 2] += a4.w * b4.z; acc[3][c + 3] += a4.w * b4.w;
            }
        }
        __syncthreads();
    }
    #pragma unroll
    for (int c4 = 0; c4 < 3; ++c4) {
        const int fc = (tx << 2) + (c4 << 6);
        const float4 bp = *(const float4*)(b + fc);
        #pragma unroll
        for (int r = 0; r < 4; ++r) {
            float4 o;
            o.x = acc[r][(c4 << 2) + 0] + bp.x;
            o.y = acc[r][(c4 << 2) + 1] + bp.y;
            o.z = acc[r][(c4 << 2) + 2] + bp.z;
            o.w = acc[r][(c4 << 2) + 3] + bp.w;
            *(float4*)(io + (size_t)(m0 + (ty << 2) + r) * CDIM + fc) = o;
        }
    }
}

// ------------------------------------------------------------------ launch
extern "C" void kernel_launch(void* const* d_in, const int* in_sizes, int n_in,
                              void* d_out, int out_size, void* d_ws, size_t ws_size,
                              hipStream_t stream) {
    const float* x     = (const float*)d_in[0];
    const float* wqkv  = (const float*)d_in[1];
    const float* bqkv  = (const float*)d_in[2];
    const float* wproj = (const float*)d_in[3];
    const float* bproj = (const float*)d_in[4];
    const float* btab  = (const float*)d_in[5];
    const int*   ridx  = (const int*)d_in[6];
    float* out = (float*)d_out;
    float* qkv = (float*)d_ws;

    const size_t need = (size_t)NROWS * QKVF * sizeof(float);   // 193.5 MiB
    if (ws_size < need) {
        hipLaunchKernelGGL(ws_too_small_sentinel, dim3(1), dim3(1), 0, stream, out);
        return;
    }
    hipLaunchKernelGGL(qkv_gemm, dim3(NROWS / 64, QKVF / 64), dim3(256), 0, stream,
                       x, wqkv, bqkv, qkv);
    hipLaunchKernelGGL(attn_flash, dim3(NQC, NH, BWIN), dim3(256), 0, stream,
                       qkv, btab, ridx, out);
    hipLaunchKernelGGL(proj_gemm_inplace, dim3(NROWS / 64), dim3(256), 0, stream,
                       out, wproj, bproj);
}

// Round 3
// 370.067 us; speedup vs baseline: 8.2552x; 3.1816x over previous
//
#include <hip/hip_runtime.h>
#include <string.h>

#define BWIN 256
#define NTOK 343
#define CDIM 192
#define NH   6
#define HD   32
#define QKVF 576
#define NROWS (BWIN * NTOK)          // 87808
#define SCALE 0.17677669529663687f   // 1/sqrt(32)

typedef unsigned short u16;
typedef short bf16x8 __attribute__((ext_vector_type(8)));
typedef float f32x4 __attribute__((ext_vector_type(4)));

// ws layout (bytes)
#define OFF_XB   101154816UL   // qkvb: [0, 101154816) u16 [87808][576]
#define OFF_OPB  134873088UL   // xb:   u16 [87808][192]
#define OFF_WQB  168591360UL   // opb:  u16 [87808][192]
#define OFF_WPB  168812544UL   // wqb:  u16 [576][192] (q rows pre-scaled)
#define OFF_BQS  168886272UL   // wpb:  u16 [192][192]
#define OFF_BM   168888576UL   // bqs:  f32 [576] (scaled); bm: u16 [6][343][352]
#define WS_NEED  170337408UL

__device__ __forceinline__ u16 f2bf(float f) {
    unsigned int u = __float_as_uint(f);
    u += 0x7FFFu + ((u >> 16) & 1u);           // RNE
    return (u16)(u >> 16);
}
__device__ __forceinline__ float bf2f(u16 h) {
    return __uint_as_float(((unsigned int)h) << 16);
}

__global__ void ws_too_small_sentinel(float* out) { out[0] = 1.0e6f; }

// ---------------------------------------------------------------- converts
__global__ __launch_bounds__(256) void cvt_x(const float* __restrict__ x,
                                             u16* __restrict__ xb, int n4) {
    const int i = blockIdx.x * 256 + threadIdx.x;
    if (i < n4) {
        const float4 v = ((const float4*)x)[i];
        ushort4 o;
        o.x = f2bf(v.x); o.y = f2bf(v.y); o.z = f2bf(v.z); o.w = f2bf(v.w);
        ((ushort4*)xb)[i] = o;
    }
}

__global__ __launch_bounds__(256) void cvt_small(
    const float* __restrict__ wq, const float* __restrict__ wp,
    const float* __restrict__ bq, const float* __restrict__ btab,
    const int* __restrict__ ridx,
    u16* __restrict__ wqb, u16* __restrict__ wpb,
    float* __restrict__ bqs, u16* __restrict__ bm)
{
    const int i = blockIdx.x * 256 + threadIdx.x;
    if (i < 110592) {                                 // w_qkv, q rows scaled
        const int f = i / 192;
        wqb[i] = f2bf(wq[i] * (f < CDIM ? SCALE : 1.0f));
    } else if (i < 147456) {
        wpb[i - 110592] = f2bf(wp[i - 110592]);
    } else if (i < 148032) {
        const int f = i - 147456;
        bqs[f] = bq[f] * (f < CDIM ? SCALE : 1.0f);
    } else if (i < 872448) {                          // bias matrix [6][343][352]
        const int u = i - 148032;
        const int hh = u / 120736;                    // 343*352
        const int rem = u - hh * 120736;
        const int q = rem / 352;
        const int j = rem - q * 352;
        const float v = (j < NTOK) ? btab[ridx[q * NTOK + j] * NH + hh] : -30.0f;
        bm[(hh * NTOK + q) * 352 + j] = f2bf(v);
    }
}

// ---------------------------------------------------------------- qkv GEMM (bf16 MFMA)
// D[m][f] = sum_k X[m][k]*Wq[f][k] + bqs[f]  -> bf16.  Tile 128(M)x96(F), K-chunks 32.
__global__ __launch_bounds__(256) void gemm_qkv(
    const u16* __restrict__ xb, const u16* __restrict__ wqb,
    const float* __restrict__ bqs, u16* __restrict__ qkvb)
{
    __shared__ u16 Xs[128][40];     // stride 40: 2-way max (free)
    __shared__ u16 Ws[96][40];
    const int m0 = blockIdx.x * 128, f0 = blockIdx.y * 96;
    const int tid = threadIdx.x;
    const int wave = tid >> 6, lane = tid & 63, quad = lane >> 4, cl = lane & 15;
    const int wm = (wave >> 1) * 64, wf = (wave & 1) * 48;
    f32x4 acc[4][3];
    #pragma unroll
    for (int t = 0; t < 4; ++t)
        #pragma unroll
        for (int s = 0; s < 3; ++s) acc[t][s] = (f32x4){0.f, 0.f, 0.f, 0.f};

    for (int kc = 0; kc < CDIM; kc += 32) {
        __syncthreads();
        #pragma unroll
        for (int u = tid; u < 512; u += 256) {
            const int row = u >> 2, seg = u & 3;
            *(float4*)&Xs[row][seg << 3] =
                *(const float4*)(xb + (size_t)(m0 + row) * CDIM + kc + (seg << 3));
        }
        for (int u = tid; u < 384; u += 256) {
            const int row = u >> 2, seg = u & 3;
            *(float4*)&Ws[row][seg << 3] =
                *(const float4*)(wqb + (size_t)(f0 + row) * CDIM + kc + (seg << 3));
        }
        __syncthreads();
        bf16x8 a[4], bb[3];
        #pragma unroll
        for (int t = 0; t < 4; ++t) a[t] = *(const bf16x8*)&Xs[wm + t * 16 + cl][quad << 3];
        #pragma unroll
        for (int s = 0; s < 3; ++s) bb[s] = *(const bf16x8*)&Ws[wf + s * 16 + cl][quad << 3];
        #pragma unroll
        for (int t = 0; t < 4; ++t)
            #pragma unroll
            for (int s = 0; s < 3; ++s)
                acc[t][s] = __builtin_amdgcn_mfma_f32_16x16x32_bf16(a[t], bb[s], acc[t][s], 0, 0, 0);
    }
    #pragma unroll
    for (int s = 0; s < 3; ++s) {
        const int col = f0 + wf + s * 16 + cl;
        const float bv = bqs[col];
        #pragma unroll
        for (int t = 0; t < 4; ++t)
            #pragma unroll
            for (int r = 0; r < 4; ++r) {
                const int row = m0 + wm + t * 16 + quad * 4 + r;
                qkvb[(size_t)row * QKVF + col] = f2bf(acc[t][s][r] + bv);
            }
    }
}

// ---------------------------------------------------------------- attention (bf16 MFMA, no-max softmax)
// Block per (window b, head h). K rows + V^T staged in LDS; per wave: 16-row
// q-tiles, 11 j-chunks of 32: S = mfma(Q,K,C=bias), P=exp(S) -> per-wave LDS
// round-trip -> PV mfma.  l accumulated in regs, shfl-reduced over 16 lanes.
__global__ __launch_bounds__(256) void attn_mfma(
    const u16* __restrict__ qkvb, const u16* __restrict__ bm,
    u16* __restrict__ opb)
{
    __shared__ u16 Ks[352][40];     // [j][k] stride 40 -> 2-way max
    __shared__ u16 Vt[32][360];     // [d][j] stride 360 -> 2-way max
    __shared__ u16 Ps[4][16][40];   // per-wave P tile [q][j-local]
    const int b = blockIdx.x, h = blockIdx.y;
    const int tid = threadIdx.x;
    const int wave = tid >> 6, lane = tid & 63, quad = lane >> 4, cl = lane & 15;
    const size_t rowbase = (size_t)b * NTOK;

    // stage K (row-major) and V (transposed), zero the j>=343 pad
    for (int u = tid; u < 1408; u += 256) {
        const int row = u >> 2, seg = u & 3;
        if (row < NTOK) {
            const size_t base = (rowbase + row) * QKVF + h * HD + (seg << 3);
            *(float4*)&Ks[row][seg << 3] = *(const float4*)(qkvb + base + CDIM);
            union { float4 f; u16 hx[8]; } vv;
            vv.f = *(const float4*)(qkvb + base + 2 * CDIM);
            #pragma unroll
            for (int e = 0; e < 8; ++e) Vt[(seg << 3) + e][row] = vv.hx[e];
        } else {
            *(float4*)&Ks[row][seg << 3] = make_float4(0.f, 0.f, 0.f, 0.f);
            #pragma unroll
            for (int e = 0; e < 8; ++e) Vt[(seg << 3) + e][row] = 0;
        }
    }
    __syncthreads();

    for (int qt = wave; qt < 22; qt += 4) {
        const int q0 = qt * 16;
        const int qrow_f = min(q0 + cl, NTOK - 1);
        const bf16x8 qa = *(const bf16x8*)(qkvb + (rowbase + qrow_f) * QKVF + h * HD + (quad << 3));
        int brow[4];
        #pragma unroll
        for (int r = 0; r < 4; ++r) brow[r] = min(q0 + quad * 4 + r, NTOK - 1);

        f32x4 o0 = {0.f,0.f,0.f,0.f}, o1 = {0.f,0.f,0.f,0.f};
        float l[4] = {0.f, 0.f, 0.f, 0.f};

        for (int jc = 0; jc < 11; ++jc) {
            const int j0 = jc * 32;
            f32x4 c0, c1;
            #pragma unroll
            for (int r = 0; r < 4; ++r) {
                const size_t bb = ((size_t)h * NTOK + brow[r]) * 352 + j0 + cl;
                c0[r] = bf2f(bm[bb]);
                c1[r] = bf2f(bm[bb + 16]);
            }
            const bf16x8 kb0 = *(const bf16x8*)&Ks[j0 + cl][quad << 3];
            const bf16x8 kb1 = *(const bf16x8*)&Ks[j0 + 16 + cl][quad << 3];
            const f32x4 s0 = __builtin_amdgcn_mfma_f32_16x16x32_bf16(qa, kb0, c0, 0, 0, 0);
            const f32x4 s1 = __builtin_amdgcn_mfma_f32_16x16x32_bf16(qa, kb1, c1, 0, 0, 0);
            #pragma unroll
            for (int r = 0; r < 4; ++r) {
                const float e0 = __expf(s0[r]);
                const float e1 = __expf(s1[r]);
                l[r] += e0 + e1;
                Ps[wave][quad * 4 + r][cl]      = f2bf(e0);
                Ps[wave][quad * 4 + r][16 + cl] = f2bf(e1);
            }
            const bf16x8 pa  = *(const bf16x8*)&Ps[wave][cl][quad << 3];
            const bf16x8 vb0 = *(const bf16x8*)&Vt[cl][j0 + (quad << 3)];
            const bf16x8 vb1 = *(const bf16x8*)&Vt[16 + cl][j0 + (quad << 3)];
            o0 = __builtin_amdgcn_mfma_f32_16x16x32_bf16(pa, vb0, o0, 0, 0, 0);
            o1 = __builtin_amdgcn_mfma_f32_16x16x32_bf16(pa, vb1, o1, 0, 0, 0);
        }
        #pragma unroll
        for (int r = 0; r < 4; ++r) {
            float lr = l[r];
            lr += __shfl_xor(lr, 1); lr += __shfl_xor(lr, 2);
            lr += __shfl_xor(lr, 4); lr += __shfl_xor(lr, 8);
            const float inv = 1.0f / lr;
            const int q = q0 + quad * 4 + r;
            if (q < NTOK) {
                const size_t base = (rowbase + q) * CDIM + h * HD;
                opb[base + cl]      = f2bf(o0[r] * inv);
                opb[base + 16 + cl] = f2bf(o1[r] * inv);
            }
        }
    }
}

// ---------------------------------------------------------------- proj GEMM (bf16 MFMA, f32 out)
__global__ __launch_bounds__(256) void gemm_proj(
    const u16* __restrict__ opb, const u16* __restrict__ wpb,
    const float* __restrict__ bp, float* __restrict__ out)
{
    __shared__ u16 Xs[128][40];
    __shared__ u16 Ws[96][40];
    const int m0 = blockIdx.x * 128, f0 = blockIdx.y * 96;
    const int tid = threadIdx.x;
    const int wave = tid >> 6, lane = tid & 63, quad = lane >> 4, cl = lane & 15;
    const int wm = (wave >> 1) * 64, wf = (wave & 1) * 48;
    f32x4 acc[4][3];
    #pragma unroll
    for (int t = 0; t < 4; ++t)
        #pragma unroll
        for (int s = 0; s < 3; ++s) acc[t][s] = (f32x4){0.f, 0.f, 0.f, 0.f};

    for (int kc = 0; kc < CDIM; kc += 32) {
        __syncthreads();
        #pragma unroll
        for (int u = tid; u < 512; u += 256) {
            const int row = u >> 2, seg = u & 3;
            *(float4*)&Xs[row][seg << 3] =
                *(const float4*)(opb + (size_t)(m0 + row) * CDIM + kc + (seg << 3));
        }
        for (int u = tid; u < 384; u += 256) {
            const int row = u >> 2, seg = u & 3;
            *(float4*)&Ws[row][seg << 3] =
                *(const float4*)(wpb + (size_t)(f0 + row) * CDIM + kc + (seg << 3));
        }
        __syncthreads();
        bf16x8 a[4], bb[3];
        #pragma unroll
        for (int t = 0; t < 4; ++t) a[t] = *(const bf16x8*)&Xs[wm + t * 16 + cl][quad << 3];
        #pragma unroll
        for (int s = 0; s < 3; ++s) bb[s] = *(const bf16x8*)&Ws[wf + s * 16 + cl][quad << 3];
        #pragma unroll
        for (int t = 0; t < 4; ++t)
            #pragma unroll
            for (int s = 0; s < 3; ++s)
                acc[t][s] = __builtin_amdgcn_mfma_f32_16x16x32_bf16(a[t], bb[s], acc[t][s], 0, 0, 0);
    }
    #pragma unroll
    for (int s = 0; s < 3; ++s) {
        const int col = f0 + wf + s * 16 + cl;
        const float bv = bp[col];
        #pragma unroll
        for (int t = 0; t < 4; ++t)
            #pragma unroll
            for (int r = 0; r < 4; ++r) {
                const int row = m0 + wm + t * 16 + quad * 4 + r;
                out[(size_t)row * CDIM + col] = acc[t][s][r] + bv;
            }
    }
}

// ---------------------------------------------------------------- launch
extern "C" void kernel_launch(void* const* d_in, const int* in_sizes, int n_in,
                              void* d_out, int out_size, void* d_ws, size_t ws_size,
                              hipStream_t stream) {
    const float* x     = (const float*)d_in[0];
    const float* wqkv  = (const float*)d_in[1];
    const float* bqkv  = (const float*)d_in[2];
    const float* wproj = (const float*)d_in[3];
    const float* bproj = (const float*)d_in[4];
    const float* btab  = (const float*)d_in[5];
    const int*   ridx  = (const int*)d_in[6];
    float* out = (float*)d_out;

    if (ws_size < WS_NEED) {
        hipLaunchKernelGGL(ws_too_small_sentinel, dim3(1), dim3(1), 0, stream, out);
        return;
    }
    char* ws = (char*)d_ws;
    u16*   qkvb = (u16*)ws;
    u16*   xb   = (u16*)(ws + OFF_XB);
    u16*   opb  = (u16*)(ws + OFF_OPB);
    u16*   wqb  = (u16*)(ws + OFF_WQB);
    u16*   wpb  = (u16*)(ws + OFF_WPB);
    float* bqs  = (float*)(ws + OFF_BQS);
    u16*   bmp  = (u16*)(ws + OFF_BM);

    hipLaunchKernelGGL(cvt_x, dim3(16464), dim3(256), 0, stream, x, xb, 4214784);
    hipLaunchKernelGGL(cvt_small, dim3(3408), dim3(256), 0, stream,
                       wqkv, wproj, bqkv, btab, ridx, wqb, wpb, bqs, bmp);
    hipLaunchKernelGGL(gemm_qkv, dim3(NROWS / 128, 6), dim3(256), 0, stream,
                       xb, wqb, bqs, qkvb);
    hipLaunchKernelGGL(attn_mfma, dim3(BWIN, NH), dim3(256), 0, stream,
                       qkvb, bmp, opb);
    hipLaunchKernelGGL(gemm_proj, dim3(NROWS / 128, 2), dim3(256), 0, stream,
                       opb, wpb, bproj, out);
}

// Round 4
// 368.854 us; speedup vs baseline: 8.2823x; 1.0033x over previous
//
#include <hip/hip_runtime.h>
#include <hip/hip_bf16.h>

#define BWIN 256
#define NTOK 343
#define CDIM 192
#define NH   6
#define HD   32
#define QKVF 576
#define NROWS (BWIN * NTOK)          // 87808
#define SCALE 0.17677669529663687f   // 1/sqrt(32)
#define LOG2E 1.4426950408889634f

typedef unsigned short u16;
typedef short bf16x8 __attribute__((ext_vector_type(8)));
typedef float f32x4 __attribute__((ext_vector_type(4)));

// ws layout (bytes)
#define OFF_XB   101154816UL   // qkvb: u16 [87808][576]
#define OFF_OPB  134873088UL   // xb:   u16 [87808][192]
#define OFF_WQB  168591360UL   // opb:  u16 [87808][192]
#define OFF_WPB  168812544UL   // wqb:  u16 [576][192] (q rows scaled by SCALE*LOG2E)
#define OFF_BQS  168886272UL   // wpb:  u16 [192][192]
#define OFF_BMF  168888576UL   // bqs: f32[576]; bmf: f32 C-frag bias [6*22*11][128][4]
#define WS_NEED  171862272UL

__device__ __forceinline__ u16 f2bf(float f) {
    unsigned int u = __float_as_uint(f);
    u += 0x7FFFu + ((u >> 16) & 1u);           // RNE
    return (u16)(u >> 16);
}

__global__ void ws_too_small_sentinel(float* out) { out[0] = 1.0e6f; }

// ---------------------------------------------------------------- converts
__global__ __launch_bounds__(256) void cvt_x(const float* __restrict__ x,
                                             u16* __restrict__ xb, int n4) {
    const int i = blockIdx.x * 256 + threadIdx.x;
    if (i < n4) {
        const float4 v = ((const float4*)x)[i];
        ushort4 o;
        o.x = f2bf(v.x); o.y = f2bf(v.y); o.z = f2bf(v.z); o.w = f2bf(v.w);
        ((ushort4*)xb)[i] = o;
    }
}

// weights + bias + bias-matrix in MFMA C-fragment layout (log2 domain)
__global__ __launch_bounds__(256) void cvt_small(
    const float* __restrict__ wq, const float* __restrict__ wp,
    const float* __restrict__ bq, const float* __restrict__ btab,
    const int* __restrict__ ridx,
    u16* __restrict__ wqb, u16* __restrict__ wpb,
    float* __restrict__ bqs, float* __restrict__ bmf)
{
    const int i = blockIdx.x * 256 + threadIdx.x;
    if (i < 110592) {                                 // w_qkv; q rows scaled
        const int f = i / 192;
        wqb[i] = f2bf(wq[i] * (f < CDIM ? SCALE * LOG2E : 1.0f));
    } else if (i < 147456) {
        wpb[i - 110592] = f2bf(wp[i - 110592]);
    } else if (i < 148032) {
        const int f = i - 147456;
        bqs[f] = bq[f] * (f < CDIM ? SCALE * LOG2E : 1.0f);
    } else if (i < 333888) {                          // bmf float4 units
        const int t4 = i - 148032;
        const int lane = t4 & 63, half = (t4 >> 6) & 1, c = t4 >> 7;
        const int jc = c % 11, qt = (c / 11) % 22, hh = c / 242;
        const int quad = lane >> 4, cl = lane & 15;
        float4 o;
        float* op = (float*)&o;
        #pragma unroll
        for (int r = 0; r < 4; ++r) {
            const int q = qt * 16 + quad * 4 + r;
            const int j = jc * 32 + half * 16 + cl;
            op[r] = (q < NTOK && j < NTOK)
                  ? btab[ridx[q * NTOK + j] * NH + hh] * LOG2E : -10000.0f;
        }
        ((float4*)bmf)[t4] = o;
    }
}

// ---------------------------------------------------------------- qkv GEMM (bf16 MFMA)
// Tile 128(M) x 96(F), K-chunks of 64 (3 iters). f = blockIdx.x so the 6
// co-dispatched f-blocks of one m-row share the X tile in L2.
__global__ __launch_bounds__(256) void gemm_qkv(
    const u16* __restrict__ xb, const u16* __restrict__ wqb,
    const float* __restrict__ bqs, u16* __restrict__ qkvb)
{
    __shared__ u16 Xs[128][72];     // stride 72: 2-way max on frag reads
    __shared__ u16 Ws[96][72];
    const int f0 = blockIdx.x * 96, m0 = blockIdx.y * 128;
    const int tid = threadIdx.x;
    const int wave = tid >> 6, lane = tid & 63, quad = lane >> 4, cl = lane & 15;
    const int wm = (wave >> 1) * 64, wf = (wave & 1) * 48;
    f32x4 acc[4][3];
    #pragma unroll
    for (int t = 0; t < 4; ++t)
        #pragma unroll
        for (int s = 0; s < 3; ++s) acc[t][s] = (f32x4){0.f, 0.f, 0.f, 0.f};

    for (int kc = 0; kc < CDIM; kc += 64) {
        __syncthreads();
        #pragma unroll
        for (int u = tid; u < 1024; u += 256) {
            const int row = u >> 3, seg = u & 7;
            *(float4*)&Xs[row][seg << 3] =
                *(const float4*)(xb + (size_t)(m0 + row) * CDIM + kc + (seg << 3));
        }
        #pragma unroll
        for (int u = tid; u < 768; u += 256) {
            const int row = u >> 3, seg = u & 7;
            *(float4*)&Ws[row][seg << 3] =
                *(const float4*)(wqb + (size_t)(f0 + row) * CDIM + kc + (seg << 3));
        }
        __syncthreads();
        #pragma unroll
        for (int ks = 0; ks < 2; ++ks) {
            bf16x8 a[4], bb[3];
            #pragma unroll
            for (int t = 0; t < 4; ++t)
                a[t] = *(const bf16x8*)&Xs[wm + t * 16 + cl][(ks << 5) + (quad << 3)];
            #pragma unroll
            for (int s = 0; s < 3; ++s)
                bb[s] = *(const bf16x8*)&Ws[wf + s * 16 + cl][(ks << 5) + (quad << 3)];
            #pragma unroll
            for (int t = 0; t < 4; ++t)
                #pragma unroll
                for (int s = 0; s < 3; ++s)
                    acc[t][s] = __builtin_amdgcn_mfma_f32_16x16x32_bf16(a[t], bb[s], acc[t][s], 0, 0, 0);
        }
    }
    #pragma unroll
    for (int s = 0; s < 3; ++s) {
        const int col = f0 + wf + s * 16 + cl;
        const float bv = bqs[col];
        #pragma unroll
        for (int t = 0; t < 4; ++t)
            #pragma unroll
            for (int r = 0; r < 4; ++r) {
                const int row = m0 + wm + t * 16 + quad * 4 + r;
                qkvb[(size_t)row * QKVF + col] = f2bf(acc[t][s][r] + bv);
            }
    }
}

// ---------------------------------------------------------------- attention
// Block per (b,h), 28 KB LDS -> 5 blocks/CU. K frags direct from global
// (L1-resident). Softmax in exp2 domain, bias = C-operand (pre-laid-out),
// l via mfma(P, ones) on the idle matrix pipe. P round-trip uses packed
// bf16 cvt + the pi(j)=(j&15)*2+(j>>4) permutation applied to both P and V^T.
__global__ __launch_bounds__(256, 5) void attn_mfma(
    const u16* __restrict__ qkvb, const float* __restrict__ bmf,
    u16* __restrict__ opb)
{
    __shared__ u16 Vt[32][360];     // [d][pi(j)] 23040 B
    __shared__ u16 Ps[4][16][40];   // per-wave P tile 5120 B
    const int b = blockIdx.x, h = blockIdx.y;
    const int tid = threadIdx.x;
    const int wave = tid >> 6, lane = tid & 63, quad = lane >> 4, cl = lane & 15;
    const size_t rowbase = (size_t)b * NTOK;

    for (int u = tid; u < 1408; u += 256) {          // stage V^T with pi-columns
        const int row = u >> 2, seg = u & 3;
        union { float4 f; u16 hx[8]; } vv;
        vv.f = make_float4(0.f, 0.f, 0.f, 0.f);
        if (row < NTOK)
            vv.f = *(const float4*)(qkvb + (rowbase + row) * QKVF + 2 * CDIM + h * HD + (seg << 3));
        const int jl = row & 31;
        const int pcol = (row & ~31) + ((jl & 15) << 1) + (jl >> 4);
        #pragma unroll
        for (int e = 0; e < 8; ++e) Vt[(seg << 3) + e][pcol] = vv.hx[e];
    }
    __syncthreads();

    bf16x8 ones;
    #pragma unroll
    for (int e = 0; e < 8; ++e) ones[e] = (short)0x3F80;   // bf16 1.0

    for (int qt = wave; qt < 22; qt += 4) {
        const int q0 = qt * 16;
        const int qrow = min(q0 + cl, NTOK - 1);
        const bf16x8 qa = *(const bf16x8*)(qkvb + (rowbase + qrow) * QKVF + h * HD + (quad << 3));
        const float* bchunk = bmf + (size_t)(h * 22 + qt) * 11 * 512;
        f32x4 o0 = {0.f,0.f,0.f,0.f}, o1 = {0.f,0.f,0.f,0.f}, lac = {0.f,0.f,0.f,0.f};

        for (int jc = 0; jc < 11; ++jc) {
            const int j0 = jc << 5;
            const f32x4 c0 = *(const f32x4*)(bchunk + jc * 512 + lane * 4);
            const f32x4 c1 = *(const f32x4*)(bchunk + jc * 512 + 256 + lane * 4);
            const bf16x8 kb0 = *(const bf16x8*)(qkvb + (rowbase + j0 + cl) * QKVF + CDIM + h * HD + (quad << 3));
            const bf16x8 kb1 = *(const bf16x8*)(qkvb + (rowbase + j0 + 16 + cl) * QKVF + CDIM + h * HD + (quad << 3));
            const f32x4 s0 = __builtin_amdgcn_mfma_f32_16x16x32_bf16(qa, kb0, c0, 0, 0, 0);
            const f32x4 s1 = __builtin_amdgcn_mfma_f32_16x16x32_bf16(qa, kb1, c1, 0, 0, 0);
            #pragma unroll
            for (int r = 0; r < 4; ++r) {
                const float e0 = __builtin_amdgcn_exp2f(s0[r]);
                const float e1 = __builtin_amdgcn_exp2f(s1[r]);
                union { __hip_bfloat162 h2; unsigned int u; } pk;
                pk.h2 = __float22bfloat162_rn(make_float2(e0, e1));
                *(unsigned int*)&Ps[wave][quad * 4 + r][cl << 1] = pk.u;   // pi cols 2cl,2cl+1
            }
            const bf16x8 pa  = *(const bf16x8*)&Ps[wave][cl][quad << 3];
            const bf16x8 vb0 = *(const bf16x8*)&Vt[cl][j0 + (quad << 3)];
            const bf16x8 vb1 = *(const bf16x8*)&Vt[16 + cl][j0 + (quad << 3)];
            o0  = __builtin_amdgcn_mfma_f32_16x16x32_bf16(pa, vb0, o0, 0, 0, 0);
            o1  = __builtin_amdgcn_mfma_f32_16x16x32_bf16(pa, vb1, o1, 0, 0, 0);
            lac = __builtin_amdgcn_mfma_f32_16x16x32_bf16(pa, ones, lac, 0, 0, 0);
        }
        #pragma unroll
        for (int r = 0; r < 4; ++r) {
            const int q = q0 + quad * 4 + r;
            if (q < NTOK) {
                const float inv = 1.0f / lac[r];     // lac row-sum, same C-row as o0/o1
                const size_t base = (rowbase + q) * CDIM + h * HD;
                opb[base + cl]      = f2bf(o0[r] * inv);
                opb[base + 16 + cl] = f2bf(o1[r] * inv);
            }
        }
    }
}

// ---------------------------------------------------------------- proj GEMM (bf16 MFMA, f32 out)
__global__ __launch_bounds__(256) void gemm_proj(
    const u16* __restrict__ opb, const u16* __restrict__ wpb,
    const float* __restrict__ bp, float* __restrict__ out)
{
    __shared__ u16 Xs[128][72];
    __shared__ u16 Ws[96][72];
    const int f0 = blockIdx.x * 96, m0 = blockIdx.y * 128;
    const int tid = threadIdx.x;
    const int wave = tid >> 6, lane = tid & 63, quad = lane >> 4, cl = lane & 15;
    const int wm = (wave >> 1) * 64, wf = (wave & 1) * 48;
    f32x4 acc[4][3];
    #pragma unroll
    for (int t = 0; t < 4; ++t)
        #pragma unroll
        for (int s = 0; s < 3; ++s) acc[t][s] = (f32x4){0.f, 0.f, 0.f, 0.f};

    for (int kc = 0; kc < CDIM; kc += 64) {
        __syncthreads();
        #pragma unroll
        for (int u = tid; u < 1024; u += 256) {
            const int row = u >> 3, seg = u & 7;
            *(float4*)&Xs[row][seg << 3] =
                *(const float4*)(opb + (size_t)(m0 + row) * CDIM + kc + (seg << 3));
        }
        #pragma unroll
        for (int u = tid; u < 768; u += 256) {
            const int row = u >> 3, seg = u & 7;
            *(float4*)&Ws[row][seg << 3] =
                *(const float4*)(wpb + (size_t)(f0 + row) * CDIM + kc + (seg << 3));
        }
        __syncthreads();
        #pragma unroll
        for (int ks = 0; ks < 2; ++ks) {
            bf16x8 a[4], bb[3];
            #pragma unroll
            for (int t = 0; t < 4; ++t)
                a[t] = *(const bf16x8*)&Xs[wm + t * 16 + cl][(ks << 5) + (quad << 3)];
            #pragma unroll
            for (int s = 0; s < 3; ++s)
                bb[s] = *(const bf16x8*)&Ws[wf + s * 16 + cl][(ks << 5) + (quad << 3)];
            #pragma unroll
            for (int t = 0; t < 4; ++t)
                #pragma unroll
                for (int s = 0; s < 3; ++s)
                    acc[t][s] = __builtin_amdgcn_mfma_f32_16x16x32_bf16(a[t], bb[s], acc[t][s], 0, 0, 0);
        }
    }
    #pragma unroll
    for (int s = 0; s < 3; ++s) {
        const int col = f0 + wf + s * 16 + cl;
        const float bv = bp[col];
        #pragma unroll
        for (int t = 0; t < 4; ++t)
            #pragma unroll
            for (int r = 0; r < 4; ++r) {
                const int row = m0 + wm + t * 16 + quad * 4 + r;
                out[(size_t)row * CDIM + col] = acc[t][s][r] + bv;
            }
    }
}

// ---------------------------------------------------------------- launch
extern "C" void kernel_launch(void* const* d_in, const int* in_sizes, int n_in,
                              void* d_out, int out_size, void* d_ws, size_t ws_size,
                              hipStream_t stream) {
    const float* x     = (const float*)d_in[0];
    const float* wqkv  = (const float*)d_in[1];
    const float* bqkv  = (const float*)d_in[2];
    const float* wproj = (const float*)d_in[3];
    const float* bproj = (const float*)d_in[4];
    const float* btab  = (const float*)d_in[5];
    const int*   ridx  = (const int*)d_in[6];
    float* out = (float*)d_out;

    if (ws_size < WS_NEED) {
        hipLaunchKernelGGL(ws_too_small_sentinel, dim3(1), dim3(1), 0, stream, out);
        return;
    }
    char* ws = (char*)d_ws;
    u16*   qkvb = (u16*)ws;
    u16*   xb   = (u16*)(ws + OFF_XB);
    u16*   opb  = (u16*)(ws + OFF_OPB);
    u16*   wqb  = (u16*)(ws + OFF_WQB);
    u16*   wpb  = (u16*)(ws + OFF_WPB);
    float* bqs  = (float*)(ws + OFF_BQS);
    float* bmf  = (float*)(ws + OFF_BMF);

    hipLaunchKernelGGL(cvt_x, dim3(16464), dim3(256), 0, stream, x, xb, 4214784);
    hipLaunchKernelGGL(cvt_small, dim3(1305), dim3(256), 0, stream,
                       wqkv, wproj, bqkv, btab, ridx, wqb, wpb, bqs, bmf);
    hipLaunchKernelGGL(gemm_qkv, dim3(6, NROWS / 128), dim3(256), 0, stream,
                       xb, wqb, bqs, qkvb);
    hipLaunchKernelGGL(attn_mfma, dim3(BWIN, NH), dim3(256), 0, stream,
                       qkvb, bmf, opb);
    hipLaunchKernelGGL(gemm_proj, dim3(2, NROWS / 128), dim3(256), 0, stream,
                       opb, wpb, bproj, out);
}

// Round 5
// 332.475 us; speedup vs baseline: 9.1886x; 1.1094x over previous
//
#include <hip/hip_runtime.h>
#include <hip/hip_bf16.h>

#define BWIN 256
#define NTOK 343
#define CDIM 192
#define NH   6
#define HD   32
#define QKVF 576
#define NROWS (BWIN * NTOK)          // 87808
#define SCALE 0.17677669529663687f   // 1/sqrt(32)
#define LOG2E 1.4426950408889634f

typedef unsigned short u16;
typedef unsigned int   u32;
typedef short bf16x8 __attribute__((ext_vector_type(8)));
typedef float f32x4 __attribute__((ext_vector_type(4)));

// ws layout (bytes)
#define OFF_QKVB 0UL                 // u16 [87808][576] = 101,154,816
#define OFF_OPB  101154816UL         // u16 [87808][192] =  33,718,272
#define OFF_WQB  134873088UL         // u16 [576][192]
#define OFF_WPB  135094272UL         // u16 [192][192]
#define OFF_BQS  135168000UL         // f32 [576]
#define OFF_BMB  135170304UL         // u16 [6][343][352] bias*LOG2E
#define WS_NEED  136619136UL

__device__ __forceinline__ u16 f2bf(float f) {
    u32 u = __float_as_uint(f);
    u += 0x7FFFu + ((u >> 16) & 1u);           // RNE
    return (u16)(u >> 16);
}
__device__ __forceinline__ float bf2f(u16 h) {
    return __uint_as_float(((u32)h) << 16);
}
__device__ __forceinline__ u32 pk2bf(float a, float b) {
    union { __hip_bfloat162 h; u32 u; } v;
    v.h = __float22bfloat162_rn(make_float2(a, b));   // lo=a, hi=b
    return v.u;
}

__global__ void ws_too_small_sentinel(float* out) { out[0] = 1.0e6f; }

// ---------------------------------------------------------------- small converts
__global__ __launch_bounds__(256) void cvt_small(
    const float* __restrict__ wq, const float* __restrict__ wp,
    const float* __restrict__ bq, const float* __restrict__ btab,
    const int* __restrict__ ridx,
    u16* __restrict__ wqb, u16* __restrict__ wpb,
    float* __restrict__ bqs, u16* __restrict__ bmb)
{
    const int i = blockIdx.x * 256 + threadIdx.x;
    if (i < 110592) {                                 // w_qkv; q rows scaled
        const int f = i / 192;
        wqb[i] = f2bf(wq[i] * (f < CDIM ? SCALE * LOG2E : 1.0f));
    } else if (i < 147456) {
        wpb[i - 110592] = f2bf(wp[i - 110592]);
    } else if (i < 148032) {
        const int f = i - 147456;
        bqs[f] = bq[f] * (f < CDIM ? SCALE * LOG2E : 1.0f);
    } else if (i < 872448) {                          // bias bf16 [6][343][352]
        const int u = i - 148032;
        const int hh = u / 120736;                    // 343*352
        const int rem = u - hh * 120736;
        const int q = rem / 352;
        const int j = rem - q * 352;
        const float v = (j < NTOK) ? btab[ridx[q * NTOK + j] * NH + hh] * LOG2E
                                   : -10000.0f;
        bmb[(hh * NTOK + q) * 352 + j] = f2bf(v);
    }
}

// ---------------------------------------------------------------- qkv GEMM
// Stages X directly from f32 (cvt fused). Epilogue: LDS transpose -> coalesced
// dwordx4 stores (replaces 48 scalar u16 strided stores per lane).
__global__ __launch_bounds__(256, 4) void gemm_qkv(
    const float* __restrict__ x, const u16* __restrict__ wqb,
    const float* __restrict__ bqs, u16* __restrict__ qkvb)
{
    __shared__ __align__(16) char smem[32256];
    u16* Xs = (u16*)smem;            // [128][72]
    u16* Ws = (u16*)(smem + 18432);  // [96][72]
    u16* Ct = (u16*)smem;            // [128][104] epilogue reuse (26624 B)
    const int f0 = blockIdx.x * 96, m0 = blockIdx.y * 128;
    const int tid = threadIdx.x;
    const int wave = tid >> 6, lane = tid & 63, g = lane >> 4, cl = lane & 15;
    const int wm = (wave >> 1) * 64, wf = (wave & 1) * 48;
    f32x4 acc[4][3];
    #pragma unroll
    for (int t = 0; t < 4; ++t)
        #pragma unroll
        for (int s = 0; s < 3; ++s) acc[t][s] = (f32x4){0.f, 0.f, 0.f, 0.f};

    for (int kc = 0; kc < CDIM; kc += 64) {
        __syncthreads();
        #pragma unroll
        for (int u = tid; u < 2048; u += 256) {       // X f32 -> bf16
            const int row = u >> 4, seg = u & 15;
            const float4 v = *(const float4*)(x + (size_t)(m0 + row) * CDIM + kc + seg * 4);
            u32* dst = (u32*)(Xs + row * 72 + seg * 4);
            dst[0] = pk2bf(v.x, v.y);
            dst[1] = pk2bf(v.z, v.w);
        }
        #pragma unroll
        for (int u = tid; u < 768; u += 256) {        // W bf16
            const int row = u >> 3, seg = u & 7;
            *(float4*)(Ws + row * 72 + seg * 8) =
                *(const float4*)(wqb + (size_t)(f0 + row) * CDIM + kc + seg * 8);
        }
        __syncthreads();
        #pragma unroll
        for (int ks = 0; ks < 2; ++ks) {
            bf16x8 a[4], bb[3];
            #pragma unroll
            for (int t = 0; t < 4; ++t)
                a[t] = *(const bf16x8*)(Xs + (wm + t * 16 + cl) * 72 + ks * 32 + g * 8);
            #pragma unroll
            for (int s = 0; s < 3; ++s)
                bb[s] = *(const bf16x8*)(Ws + (wf + s * 16 + cl) * 72 + ks * 32 + g * 8);
            #pragma unroll
            for (int t = 0; t < 4; ++t)
                #pragma unroll
                for (int s = 0; s < 3; ++s)
                    acc[t][s] = __builtin_amdgcn_mfma_f32_16x16x32_bf16(a[t], bb[s], acc[t][s], 0, 0, 0);
        }
    }
    __syncthreads();
    #pragma unroll
    for (int s = 0; s < 3; ++s) {
        const float bv = bqs[f0 + wf + s * 16 + cl];
        #pragma unroll
        for (int t = 0; t < 4; ++t) {
            const int row = wm + t * 16 + g * 4;
            const int col = wf + s * 16 + cl;
            const u32 p01 = pk2bf(acc[t][s][0] + bv, acc[t][s][1] + bv);
            const u32 p23 = pk2bf(acc[t][s][2] + bv, acc[t][s][3] + bv);
            Ct[(row + 0) * 104 + col] = (u16)p01;
            Ct[(row + 1) * 104 + col] = (u16)(p01 >> 16);
            Ct[(row + 2) * 104 + col] = (u16)p23;
            Ct[(row + 3) * 104 + col] = (u16)(p23 >> 16);
        }
    }
    __syncthreads();
    #pragma unroll
    for (int p = 0; p < 6; ++p) {                     // coalesced stores
        const int u = tid + 256 * p;
        const int row = u / 12, c = u - row * 12;
        *(float4*)(qkvb + (size_t)(m0 + row) * QKVF + f0 + c * 8) =
            *(const float4*)(Ct + row * 104 + c * 8);
    }
}

// ---------------------------------------------------------------- attention
// S^T formulation: mfma(A=K, B=Q, C=bias^T) -> P^T is directly the PV
// A-operand (sigma-permuted V^T in LDS). No P LDS round-trip, no atomics.
// Dual q-tile per wave shares K loads + V ds_reads. l via mfma(P, ones).
__global__ __launch_bounds__(256, 4) void attn_mfma(
    const u16* __restrict__ qkvb, const u16* __restrict__ bmb,
    u16* __restrict__ opb)
{
    __shared__ u16 Vt[HD][360];      // [d][j-slot] 23040 B
    __shared__ u16 Os[4][16][32];    // per-wave O staging 4096 B
    const int b = blockIdx.x, h = blockIdx.y;
    const int tid = threadIdx.x;
    const int wave = tid >> 6, lane = tid & 63, g = lane >> 4, cl = lane & 15;
    const size_t rowbase = (size_t)b * NTOK;

    for (int u = tid; u < 1408; u += 256) {           // V stage, sigma slots
        const int row = u >> 2, seg = u & 3;
        union { float4 f; u16 hx[8]; } vv;
        vv.f = make_float4(0.f, 0.f, 0.f, 0.f);
        if (row < NTOK)
            vv.f = *(const float4*)(qkvb + (rowbase + row) * QKVF + 2 * CDIM + h * HD + seg * 8);
        const int jl = row & 31;
        const int slot = (jl < 16) ? ((jl >> 2) << 3) + (jl & 3)
                                   : (((jl - 16) >> 2) << 3) + 4 + (jl & 3);
        const int pcol = (row & ~31) + slot;
        #pragma unroll
        for (int e = 0; e < 8; ++e) Vt[seg * 8 + e][pcol] = vv.hx[e];
    }
    __syncthreads();

    bf16x8 ones;
    #pragma unroll
    for (int e = 0; e < 8; ++e) ones[e] = (short)0x3F80;

    for (int base = wave * 2; base < 22; base += 8) { // exactly 11 pairs total
        const int q0a = base * 16, q0b = q0a + 16;
        const bf16x8 qa0 = *(const bf16x8*)(qkvb + (rowbase + min(q0a + cl, NTOK - 1)) * QKVF + h * HD + g * 8);
        const bf16x8 qa1 = *(const bf16x8*)(qkvb + (rowbase + min(q0b + cl, NTOK - 1)) * QKVF + h * HD + g * 8);
        const u16* browA = bmb + ((size_t)h * NTOK + min(q0a + cl, NTOK - 1)) * 352;
        const u16* browB = bmb + ((size_t)h * NTOK + min(q0b + cl, NTOK - 1)) * 352;

        // prefetch chunk 0
        bf16x8 kb0 = *(const bf16x8*)(qkvb + (rowbase + cl) * QKVF + CDIM + h * HD + g * 8);
        bf16x8 kb1 = *(const bf16x8*)(qkvb + (rowbase + 16 + cl) * QKVF + CDIM + h * HD + g * 8);
        ushort4 bA0 = *(const ushort4*)(browA + g * 4);
        ushort4 bA1 = *(const ushort4*)(browA + 16 + g * 4);
        ushort4 bB0 = *(const ushort4*)(browB + g * 4);
        ushort4 bB1 = *(const ushort4*)(browB + 16 + g * 4);

        f32x4 oA0 = {0,0,0,0}, oA1 = {0,0,0,0}, lA = {0,0,0,0};
        f32x4 oB0 = {0,0,0,0}, oB1 = {0,0,0,0}, lB = {0,0,0,0};

        for (int jc = 0; jc < 11; ++jc) {
            const int j0 = jc * 32;
            const bf16x8 ck0 = kb0, ck1 = kb1;
            const ushort4 cA0 = bA0, cA1 = bA1, cB0 = bB0, cB1 = bB1;
            if (jc < 10) {
                const int jn = j0 + 32;
                kb0 = *(const bf16x8*)(qkvb + (rowbase + min(jn + cl, NTOK - 1)) * QKVF + CDIM + h * HD + g * 8);
                kb1 = *(const bf16x8*)(qkvb + (rowbase + min(jn + 16 + cl, NTOK - 1)) * QKVF + CDIM + h * HD + g * 8);
                bA0 = *(const ushort4*)(browA + jn + g * 4);
                bA1 = *(const ushort4*)(browA + jn + 16 + g * 4);
                bB0 = *(const ushort4*)(browB + jn + g * 4);
                bB1 = *(const ushort4*)(browB + jn + 16 + g * 4);
            }
            const bf16x8 vb0 = *(const bf16x8*)&Vt[cl][j0 + g * 8];
            const bf16x8 vb1 = *(const bf16x8*)&Vt[16 + cl][j0 + g * 8];

            // ---- q-tile A
            {
                f32x4 c0 = { bf2f(cA0.x), bf2f(cA0.y), bf2f(cA0.z), bf2f(cA0.w) };
                f32x4 c1 = { bf2f(cA1.x), bf2f(cA1.y), bf2f(cA1.z), bf2f(cA1.w) };
                const f32x4 s0 = __builtin_amdgcn_mfma_f32_16x16x32_bf16(ck0, qa0, c0, 0, 0, 0);
                const f32x4 s1 = __builtin_amdgcn_mfma_f32_16x16x32_bf16(ck1, qa0, c1, 0, 0, 0);
                union { bf16x8 v; u32 w[4]; } pa;
                pa.w[0] = pk2bf(__builtin_amdgcn_exp2f(s0[0]), __builtin_amdgcn_exp2f(s0[1]));
                pa.w[1] = pk2bf(__builtin_amdgcn_exp2f(s0[2]), __builtin_amdgcn_exp2f(s0[3]));
                pa.w[2] = pk2bf(__builtin_amdgcn_exp2f(s1[0]), __builtin_amdgcn_exp2f(s1[1]));
                pa.w[3] = pk2bf(__builtin_amdgcn_exp2f(s1[2]), __builtin_amdgcn_exp2f(s1[3]));
                oA0 = __builtin_amdgcn_mfma_f32_16x16x32_bf16(pa.v, vb0, oA0, 0, 0, 0);
                oA1 = __builtin_amdgcn_mfma_f32_16x16x32_bf16(pa.v, vb1, oA1, 0, 0, 0);
                lA  = __builtin_amdgcn_mfma_f32_16x16x32_bf16(pa.v, ones, lA, 0, 0, 0);
            }
            // ---- q-tile B
            {
                f32x4 c0 = { bf2f(cB0.x), bf2f(cB0.y), bf2f(cB0.z), bf2f(cB0.w) };
                f32x4 c1 = { bf2f(cB1.x), bf2f(cB1.y), bf2f(cB1.z), bf2f(cB1.w) };
                const f32x4 s0 = __builtin_amdgcn_mfma_f32_16x16x32_bf16(ck0, qa1, c0, 0, 0, 0);
                const f32x4 s1 = __builtin_amdgcn_mfma_f32_16x16x32_bf16(ck1, qa1, c1, 0, 0, 0);
                union { bf16x8 v; u32 w[4]; } pa;
                pa.w[0] = pk2bf(__builtin_amdgcn_exp2f(s0[0]), __builtin_amdgcn_exp2f(s0[1]));
                pa.w[1] = pk2bf(__builtin_amdgcn_exp2f(s0[2]), __builtin_amdgcn_exp2f(s0[3]));
                pa.w[2] = pk2bf(__builtin_amdgcn_exp2f(s1[0]), __builtin_amdgcn_exp2f(s1[1]));
                pa.w[3] = pk2bf(__builtin_amdgcn_exp2f(s1[2]), __builtin_amdgcn_exp2f(s1[3]));
                oB0 = __builtin_amdgcn_mfma_f32_16x16x32_bf16(pa.v, vb0, oB0, 0, 0, 0);
                oB1 = __builtin_amdgcn_mfma_f32_16x16x32_bf16(pa.v, vb1, oB1, 0, 0, 0);
                lB  = __builtin_amdgcn_mfma_f32_16x16x32_bf16(pa.v, ones, lB, 0, 0, 0);
            }
        }
        // epilogue: per-wave LDS transpose -> coalesced 16B stores
        #pragma unroll
        for (int half = 0; half < 2; ++half) {
            const f32x4 o0 = half ? oB0 : oA0;
            const f32x4 o1 = half ? oB1 : oA1;
            const f32x4 lc = half ? lB : lA;
            const int q0 = half ? q0b : q0a;
            #pragma unroll
            for (int r = 0; r < 4; ++r) {
                const float inv = 1.0f / lc[r];
                Os[wave][g * 4 + r][cl]      = f2bf(o0[r] * inv);
                Os[wave][g * 4 + r][16 + cl] = f2bf(o1[r] * inv);
            }
            const int row = lane >> 2, cg = (lane & 3) * 8;
            const int q = q0 + row;
            if (q < NTOK)
                *(float4*)(opb + (rowbase + q) * CDIM + h * HD + cg) =
                    *(const float4*)&Os[wave][row][cg];
        }
    }
}

// ---------------------------------------------------------------- proj GEMM (f32 out, 2-pass LDS-transpose epilogue)
__global__ __launch_bounds__(256, 4) void gemm_proj(
    const u16* __restrict__ opb, const u16* __restrict__ wpb,
    const float* __restrict__ bp, float* __restrict__ out)
{
    __shared__ __align__(16) char smem[32256];
    u16*   Xs = (u16*)smem;            // [128][72]
    u16*   Ws = (u16*)(smem + 18432);  // [96][72]
    float* Cf = (float*)smem;          // [64][104] f32 (26624 B)
    const int f0 = blockIdx.x * 96, m0 = blockIdx.y * 128;
    const int tid = threadIdx.x;
    const int wave = tid >> 6, lane = tid & 63, g = lane >> 4, cl = lane & 15;
    const int wm = (wave >> 1) * 64, wf = (wave & 1) * 48;
    f32x4 acc[4][3];
    #pragma unroll
    for (int t = 0; t < 4; ++t)
        #pragma unroll
        for (int s = 0; s < 3; ++s) acc[t][s] = (f32x4){0.f, 0.f, 0.f, 0.f};

    for (int kc = 0; kc < CDIM; kc += 64) {
        __syncthreads();
        #pragma unroll
        for (int u = tid; u < 1024; u += 256) {
            const int row = u >> 3, seg = u & 7;
            *(float4*)(Xs + row * 72 + seg * 8) =
                *(const float4*)(opb + (size_t)(m0 + row) * CDIM + kc + seg * 8);
        }
        #pragma unroll
        for (int u = tid; u < 768; u += 256) {
            const int row = u >> 3, seg = u & 7;
            *(float4*)(Ws + row * 72 + seg * 8) =
                *(const float4*)(wpb + (size_t)(f0 + row) * CDIM + kc + seg * 8);
        }
        __syncthreads();
        #pragma unroll
        for (int ks = 0; ks < 2; ++ks) {
            bf16x8 a[4], bb[3];
            #pragma unroll
            for (int t = 0; t < 4; ++t)
                a[t] = *(const bf16x8*)(Xs + (wm + t * 16 + cl) * 72 + ks * 32 + g * 8);
            #pragma unroll
            for (int s = 0; s < 3; ++s)
                bb[s] = *(const bf16x8*)(Ws + (wf + s * 16 + cl) * 72 + ks * 32 + g * 8);
            #pragma unroll
            for (int t = 0; t < 4; ++t)
                #pragma unroll
                for (int s = 0; s < 3; ++s)
                    acc[t][s] = __builtin_amdgcn_mfma_f32_16x16x32_bf16(a[t], bb[s], acc[t][s], 0, 0, 0);
        }
    }
    #pragma unroll
    for (int half = 0; half < 2; ++half) {
        __syncthreads();
        if ((wave >> 1) == half) {
            #pragma unroll
            for (int s = 0; s < 3; ++s) {
                const float bv = bp[f0 + wf + s * 16 + cl];
                #pragma unroll
                for (int t = 0; t < 4; ++t)
                    #pragma unroll
                    for (int r = 0; r < 4; ++r)
                        Cf[(t * 16 + g * 4 + r) * 104 + wf + s * 16 + cl] = acc[t][s][r] + bv;
            }
        }
        __syncthreads();
        #pragma unroll
        for (int p = 0; p < 6; ++p) {
            const int u = tid + 256 * p;
            const int row = u / 24, c = u - row * 24;
            *(float4*)(out + (size_t)(m0 + half * 64 + row) * CDIM + f0 + c * 4) =
                *(const float4*)(Cf + row * 104 + c * 4);
        }
    }
}

// ---------------------------------------------------------------- launch
extern "C" void kernel_launch(void* const* d_in, const int* in_sizes, int n_in,
                              void* d_out, int out_size, void* d_ws, size_t ws_size,
                              hipStream_t stream) {
    const float* x     = (const float*)d_in[0];
    const float* wqkv  = (const float*)d_in[1];
    const float* bqkv  = (const float*)d_in[2];
    const float* wproj = (const float*)d_in[3];
    const float* bproj = (const float*)d_in[4];
    const float* btab  = (const float*)d_in[5];
    const int*   ridx  = (const int*)d_in[6];
    float* out = (float*)d_out;

    if (ws_size < WS_NEED) {
        hipLaunchKernelGGL(ws_too_small_sentinel, dim3(1), dim3(1), 0, stream, out);
        return;
    }
    char* ws = (char*)d_ws;
    u16*   qkvb = (u16*)(ws + OFF_QKVB);
    u16*   opb  = (u16*)(ws + OFF_OPB);
    u16*   wqb  = (u16*)(ws + OFF_WQB);
    u16*   wpb  = (u16*)(ws + OFF_WPB);
    float* bqs  = (float*)(ws + OFF_BQS);
    u16*   bmb  = (u16*)(ws + OFF_BMB);

    hipLaunchKernelGGL(cvt_small, dim3(3408), dim3(256), 0, stream,
                       wqkv, wproj, bqkv, btab, ridx, wqb, wpb, bqs, bmb);
    hipLaunchKernelGGL(gemm_qkv, dim3(6, NROWS / 128), dim3(256), 0, stream,
                       x, wqb, bqs, qkvb);
    hipLaunchKernelGGL(attn_mfma, dim3(BWIN, NH), dim3(256), 0, stream,
                       qkvb, bmb, opb);
    hipLaunchKernelGGL(gemm_proj, dim3(2, NROWS / 128), dim3(256), 0, stream,
                       opb, wpb, bproj, out);
}

// Round 7
// 315.270 us; speedup vs baseline: 9.6900x; 1.0546x over previous
//
#include <hip/hip_runtime.h>
#include <hip/hip_bf16.h>

#define BWIN 256
#define NTOK 343
#define CDIM 192
#define NH   6
#define HD   32
#define QKVF 576
#define NROWS (BWIN * NTOK)          // 87808
#define SCALE 0.17677669529663687f   // 1/sqrt(32)
#define LOG2E 1.4426950408889634f

typedef unsigned short u16;
typedef unsigned int   u32;
typedef short bf16x8 __attribute__((ext_vector_type(8)));
typedef float f32x4 __attribute__((ext_vector_type(4)));

// ws layout (bytes)
#define OFF_QKVB 0UL                 // u16 [87808][576] = 101,154,816
#define OFF_OPB  101154816UL         // u16 [87808][192] =  33,718,272
#define OFF_WQB  134873088UL         // u16 [576][192]
#define OFF_WPB  135094272UL         // u16 [192][192]
#define OFF_BQS  135168000UL         // f32 [576]
#define OFF_BMB  135170304UL         // u16 [6][343][352] bias*LOG2E
#define WS_NEED  136619136UL

__device__ __forceinline__ u16 f2bf(float f) {
    u32 u = __float_as_uint(f);
    u += 0x7FFFu + ((u >> 16) & 1u);           // RNE
    return (u16)(u >> 16);
}
__device__ __forceinline__ float bf2f(u16 h) {
    return __uint_as_float(((u32)h) << 16);
}
__device__ __forceinline__ u32 pk2bf(float a, float b) {
    union { __hip_bfloat162 h; u32 u; } v;
    v.h = __float22bfloat162_rn(make_float2(a, b));   // lo=a, hi=b
    return v.u;
}

__global__ void ws_too_small_sentinel(float* out) { out[0] = 1.0e6f; }

// ---------------------------------------------------------------- small converts
__global__ __launch_bounds__(256) void cvt_small(
    const float* __restrict__ wq, const float* __restrict__ wp,
    const float* __restrict__ bq, const float* __restrict__ btab,
    const int* __restrict__ ridx,
    u16* __restrict__ wqb, u16* __restrict__ wpb,
    float* __restrict__ bqs, u16* __restrict__ bmb)
{
    const int i = blockIdx.x * 256 + threadIdx.x;
    if (i < 110592) {                                 // w_qkv; q rows scaled
        const int f = i / 192;
        wqb[i] = f2bf(wq[i] * (f < CDIM ? SCALE * LOG2E : 1.0f));
    } else if (i < 147456) {
        wpb[i - 110592] = f2bf(wp[i - 110592]);
    } else if (i < 148032) {
        const int f = i - 147456;
        bqs[f] = bq[f] * (f < CDIM ? SCALE * LOG2E : 1.0f);
    } else if (i < 872448) {                          // bias bf16 [6][343][352]
        const int u = i - 148032;
        const int hh = u / 120736;                    // 343*352
        const int rem = u - hh * 120736;
        const int q = rem / 352;
        const int j = rem - q * 352;
        const float v = (j < NTOK) ? btab[ridx[q * NTOK + j] * NH + hh] * LOG2E
                                   : -10000.0f;
        bmb[(hh * NTOK + q) * 352 + j] = f2bf(v);
    }
}

// ---------------------------------------------------------------- qkv GEMM
// X tile (128 rows x full K=192) staged ONCE into LDS (f32->bf16 fused).
// W fragments read directly from global (f-chunk 37KB, L1/L2-resident).
// K-loop has ZERO barriers: ds_read_b128 + global dwordx4 + mfma only.
__global__ __launch_bounds__(256, 3) void gemm_qkv(
    const float* __restrict__ x, const u16* __restrict__ wqb,
    const float* __restrict__ bqs, u16* __restrict__ qkvb)
{
    __shared__ __align__(16) u16 smem[128 * 200];     // Xs [128][200]; epilogue Ct [128][104]
    u16* Xs = smem;
    u16* Ct = smem;
    const int f0 = blockIdx.x * 96, m0 = blockIdx.y * 128;
    const int tid = threadIdx.x;
    const int wave = tid >> 6, lane = tid & 63, g = lane >> 4, cl = lane & 15;
    const int wm = (wave >> 1) * 64, wf = (wave & 1) * 48;

    // stage X once: 128 rows x 48 float4 units = 6144 (24 passes of 256)
    #pragma unroll
    for (int p = 0; p < 24; ++p) {
        const int u = tid + 256 * p;
        const int row = u / 48, c = u - row * 48;
        const float4 v = *(const float4*)(x + (size_t)(m0 + row) * CDIM + c * 4);
        *(uint2*)(Xs + row * 200 + c * 4) = make_uint2(pk2bf(v.x, v.y), pk2bf(v.z, v.w));
    }
    __syncthreads();

    f32x4 acc[4][3];
    #pragma unroll
    for (int t = 0; t < 4; ++t)
        #pragma unroll
        for (int s = 0; s < 3; ++s) acc[t][s] = (f32x4){0.f, 0.f, 0.f, 0.f};

    const u16* wbase = wqb + (size_t)(f0 + wf + cl) * CDIM + g * 8;
    #pragma unroll
    for (int kk = 0; kk < 6; ++kk) {
        const int kcol = kk * 32;
        bf16x8 a[4], bb[3];
        #pragma unroll
        for (int s = 0; s < 3; ++s)
            bb[s] = *(const bf16x8*)(wbase + (size_t)(s * 16) * CDIM + kcol);
        #pragma unroll
        for (int t = 0; t < 4; ++t)
            a[t] = *(const bf16x8*)(Xs + (wm + t * 16 + cl) * 200 + kcol + g * 8);
        #pragma unroll
        for (int t = 0; t < 4; ++t)
            #pragma unroll
            for (int s = 0; s < 3; ++s)
                acc[t][s] = __builtin_amdgcn_mfma_f32_16x16x32_bf16(a[t], bb[s], acc[t][s], 0, 0, 0);
    }

    __syncthreads();                                  // Xs reads done; reuse as Ct
    #pragma unroll
    for (int s = 0; s < 3; ++s) {
        const float bv = bqs[f0 + wf + s * 16 + cl];
        #pragma unroll
        for (int t = 0; t < 4; ++t) {
            const int row = wm + t * 16 + g * 4;
            const int col = wf + s * 16 + cl;
            const u32 p01 = pk2bf(acc[t][s][0] + bv, acc[t][s][1] + bv);
            const u32 p23 = pk2bf(acc[t][s][2] + bv, acc[t][s][3] + bv);
            Ct[(row + 0) * 104 + col] = (u16)p01;
            Ct[(row + 1) * 104 + col] = (u16)(p01 >> 16);
            Ct[(row + 2) * 104 + col] = (u16)p23;
            Ct[(row + 3) * 104 + col] = (u16)(p23 >> 16);
        }
    }
    __syncthreads();
    #pragma unroll
    for (int p = 0; p < 6; ++p) {                     // coalesced 16B stores
        const int u = tid + 256 * p;
        const int row = u / 12, c = u - row * 12;
        *(float4*)(qkvb + (size_t)(m0 + row) * QKVF + f0 + c * 8) =
            *(const float4*)(Ct + row * 104 + c * 8);
    }
}

// ---------------------------------------------------------------- attention (unchanged from R5)
__global__ __launch_bounds__(256, 4) void attn_mfma(
    const u16* __restrict__ qkvb, const u16* __restrict__ bmb,
    u16* __restrict__ opb)
{
    __shared__ u16 Vt[HD][360];      // [d][j-slot] 23040 B
    __shared__ u16 Os[4][16][32];    // per-wave O staging 4096 B
    const int b = blockIdx.x, h = blockIdx.y;
    const int tid = threadIdx.x;
    const int wave = tid >> 6, lane = tid & 63, g = lane >> 4, cl = lane & 15;
    const size_t rowbase = (size_t)b * NTOK;

    for (int u = tid; u < 1408; u += 256) {           // V stage, sigma slots
        const int row = u >> 2, seg = u & 3;
        union { float4 f; u16 hx[8]; } vv;
        vv.f = make_float4(0.f, 0.f, 0.f, 0.f);
        if (row < NTOK)
            vv.f = *(const float4*)(qkvb + (rowbase + row) * QKVF + 2 * CDIM + h * HD + seg * 8);
        const int jl = row & 31;
        const int slot = (jl < 16) ? ((jl >> 2) << 3) + (jl & 3)
                                   : (((jl - 16) >> 2) << 3) + 4 + (jl & 3);
        const int pcol = (row & ~31) + slot;
        #pragma unroll
        for (int e = 0; e < 8; ++e) Vt[seg * 8 + e][pcol] = vv.hx[e];
    }
    __syncthreads();

    bf16x8 ones;
    #pragma unroll
    for (int e = 0; e < 8; ++e) ones[e] = (short)0x3F80;

    for (int base = wave * 2; base < 22; base += 8) { // 11 pairs total
        const int q0a = base * 16, q0b = q0a + 16;
        const bf16x8 qa0 = *(const bf16x8*)(qkvb + (rowbase + min(q0a + cl, NTOK - 1)) * QKVF + h * HD + g * 8);
        const bf16x8 qa1 = *(const bf16x8*)(qkvb + (rowbase + min(q0b + cl, NTOK - 1)) * QKVF + h * HD + g * 8);
        const u16* browA = bmb + ((size_t)h * NTOK + min(q0a + cl, NTOK - 1)) * 352;
        const u16* browB = bmb + ((size_t)h * NTOK + min(q0b + cl, NTOK - 1)) * 352;

        bf16x8 kb0 = *(const bf16x8*)(qkvb + (rowbase + cl) * QKVF + CDIM + h * HD + g * 8);
        bf16x8 kb1 = *(const bf16x8*)(qkvb + (rowbase + 16 + cl) * QKVF + CDIM + h * HD + g * 8);
        ushort4 bA0 = *(const ushort4*)(browA + g * 4);
        ushort4 bA1 = *(const ushort4*)(browA + 16 + g * 4);
        ushort4 bB0 = *(const ushort4*)(browB + g * 4);
        ushort4 bB1 = *(const ushort4*)(browB + 16 + g * 4);

        f32x4 oA0 = {0,0,0,0}, oA1 = {0,0,0,0}, lA = {0,0,0,0};
        f32x4 oB0 = {0,0,0,0}, oB1 = {0,0,0,0}, lB = {0,0,0,0};

        for (int jc = 0; jc < 11; ++jc) {
            const int j0 = jc * 32;
            const bf16x8 ck0 = kb0, ck1 = kb1;
            const ushort4 cA0 = bA0, cA1 = bA1, cB0 = bB0, cB1 = bB1;
            if (jc < 10) {
                const int jn = j0 + 32;
                kb0 = *(const bf16x8*)(qkvb + (rowbase + min(jn + cl, NTOK - 1)) * QKVF + CDIM + h * HD + g * 8);
                kb1 = *(const bf16x8*)(qkvb + (rowbase + min(jn + 16 + cl, NTOK - 1)) * QKVF + CDIM + h * HD + g * 8);
                bA0 = *(const ushort4*)(browA + jn + g * 4);
                bA1 = *(const ushort4*)(browA + jn + 16 + g * 4);
                bB0 = *(const ushort4*)(browB + jn + g * 4);
                bB1 = *(const ushort4*)(browB + jn + 16 + g * 4);
            }
            const bf16x8 vb0 = *(const bf16x8*)&Vt[cl][j0 + g * 8];
            const bf16x8 vb1 = *(const bf16x8*)&Vt[16 + cl][j0 + g * 8];

            {
                f32x4 c0 = { bf2f(cA0.x), bf2f(cA0.y), bf2f(cA0.z), bf2f(cA0.w) };
                f32x4 c1 = { bf2f(cA1.x), bf2f(cA1.y), bf2f(cA1.z), bf2f(cA1.w) };
                const f32x4 s0 = __builtin_amdgcn_mfma_f32_16x16x32_bf16(ck0, qa0, c0, 0, 0, 0);
                const f32x4 s1 = __builtin_amdgcn_mfma_f32_16x16x32_bf16(ck1, qa0, c1, 0, 0, 0);
                union { bf16x8 v; u32 w[4]; } pa;
                pa.w[0] = pk2bf(__builtin_amdgcn_exp2f(s0[0]), __builtin_amdgcn_exp2f(s0[1]));
                pa.w[1] = pk2bf(__builtin_amdgcn_exp2f(s0[2]), __builtin_amdgcn_exp2f(s0[3]));
                pa.w[2] = pk2bf(__builtin_amdgcn_exp2f(s1[0]), __builtin_amdgcn_exp2f(s1[1]));
                pa.w[3] = pk2bf(__builtin_amdgcn_exp2f(s1[2]), __builtin_amdgcn_exp2f(s1[3]));
                oA0 = __builtin_amdgcn_mfma_f32_16x16x32_bf16(pa.v, vb0, oA0, 0, 0, 0);
                oA1 = __builtin_amdgcn_mfma_f32_16x16x32_bf16(pa.v, vb1, oA1, 0, 0, 0);
                lA  = __builtin_amdgcn_mfma_f32_16x16x32_bf16(pa.v, ones, lA, 0, 0, 0);
            }
            {
                f32x4 c0 = { bf2f(cB0.x), bf2f(cB0.y), bf2f(cB0.z), bf2f(cB0.w) };
                f32x4 c1 = { bf2f(cB1.x), bf2f(cB1.y), bf2f(cB1.z), bf2f(cB1.w) };
                const f32x4 s0 = __builtin_amdgcn_mfma_f32_16x16x32_bf16(ck0, qa1, c0, 0, 0, 0);
                const f32x4 s1 = __builtin_amdgcn_mfma_f32_16x16x32_bf16(ck1, qa1, c1, 0, 0, 0);
                union { bf16x8 v; u32 w[4]; } pa;
                pa.w[0] = pk2bf(__builtin_amdgcn_exp2f(s0[0]), __builtin_amdgcn_exp2f(s0[1]));
                pa.w[1] = pk2bf(__builtin_amdgcn_exp2f(s0[2]), __builtin_amdgcn_exp2f(s0[3]));
                pa.w[2] = pk2bf(__builtin_amdgcn_exp2f(s1[0]), __builtin_amdgcn_exp2f(s1[1]));
                pa.w[3] = pk2bf(__builtin_amdgcn_exp2f(s1[2]), __builtin_amdgcn_exp2f(s1[3]));
                oB0 = __builtin_amdgcn_mfma_f32_16x16x32_bf16(pa.v, vb0, oB0, 0, 0, 0);
                oB1 = __builtin_amdgcn_mfma_f32_16x16x32_bf16(pa.v, vb1, oB1, 0, 0, 0);
                lB  = __builtin_amdgcn_mfma_f32_16x16x32_bf16(pa.v, ones, lB, 0, 0, 0);
            }
        }
        #pragma unroll
        for (int half = 0; half < 2; ++half) {
            const f32x4 o0 = half ? oB0 : oA0;
            const f32x4 o1 = half ? oB1 : oA1;
            const f32x4 lc = half ? lB : lA;
            const int q0 = half ? q0b : q0a;
            #pragma unroll
            for (int r = 0; r < 4; ++r) {
                const float inv = 1.0f / lc[r];
                Os[wave][g * 4 + r][cl]      = f2bf(o0[r] * inv);
                Os[wave][g * 4 + r][16 + cl] = f2bf(o1[r] * inv);
            }
            const int row = lane >> 2, cg = (lane & 3) * 8;
            const int q = q0 + row;
            if (q < NTOK)
                *(float4*)(opb + (rowbase + q) * CDIM + h * HD + cg) =
                    *(const float4*)&Os[wave][row][cg];
        }
    }
}

// ---------------------------------------------------------------- proj GEMM
// Single-stage: opb tile staged once, W frags from global, barrier-free
// K-loop, f32 out via 2-pass LDS-transpose epilogue.
__global__ __launch_bounds__(256, 3) void gemm_proj(
    const u16* __restrict__ opb, const u16* __restrict__ wpb,
    const float* __restrict__ bp, float* __restrict__ out)
{
    __shared__ __align__(16) u16 smem[128 * 200];
    u16*   Xs = smem;
    float* Cf = (float*)smem;                         // [64][104] f32
    const int f0 = blockIdx.x * 96, m0 = blockIdx.y * 128;
    const int tid = threadIdx.x;
    const int wave = tid >> 6, lane = tid & 63, g = lane >> 4, cl = lane & 15;
    const int wm = (wave >> 1) * 64, wf = (wave & 1) * 48;

    // stage once: 128 rows x 24 float4 units = 3072
    #pragma unroll
    for (int p = 0; p < 12; ++p) {
        const int u = tid + 256 * p;
        const int row = u / 24, c = u - row * 24;
        *(float4*)(Xs + row * 200 + c * 8) =
            *(const float4*)(opb + (size_t)(m0 + row) * CDIM + c * 8);
    }
    __syncthreads();

    f32x4 acc[4][3];
    #pragma unroll
    for (int t = 0; t < 4; ++t)
        #pragma unroll
        for (int s = 0; s < 3; ++s) acc[t][s] = (f32x4){0.f, 0.f, 0.f, 0.f};

    const u16* wbase = wpb + (size_t)(f0 + wf + cl) * CDIM + g * 8;
    #pragma unroll
    for (int kk = 0; kk < 6; ++kk) {
        const int kcol = kk * 32;
        bf16x8 a[4], bb[3];
        #pragma unroll
        for (int s = 0; s < 3; ++s)
            bb[s] = *(const bf16x8*)(wbase + (size_t)(s * 16) * CDIM + kcol);
        #pragma unroll
        for (int t = 0; t < 4; ++t)
            a[t] = *(const bf16x8*)(Xs + (wm + t * 16 + cl) * 200 + kcol + g * 8);
        #pragma unroll
        for (int t = 0; t < 4; ++t)
            #pragma unroll
            for (int s = 0; s < 3; ++s)
                acc[t][s] = __builtin_amdgcn_mfma_f32_16x16x32_bf16(a[t], bb[s], acc[t][s], 0, 0, 0);
    }

    #pragma unroll
    for (int half = 0; half < 2; ++half) {
        __syncthreads();
        if ((wave >> 1) == half) {
            #pragma unroll
            for (int s = 0; s < 3; ++s) {
                const float bv = bp[f0 + wf + s * 16 + cl];
                #pragma unroll
                for (int t = 0; t < 4; ++t)
                    #pragma unroll
                    for (int r = 0; r < 4; ++r)
                        Cf[(t * 16 + g * 4 + r) * 104 + wf + s * 16 + cl] = acc[t][s][r] + bv;
            }
        }
        __syncthreads();
        #pragma unroll
        for (int p = 0; p < 6; ++p) {
            const int u = tid + 256 * p;
            const int row = u / 24, c = u - row * 24;
            *(float4*)(out + (size_t)(m0 + half * 64 + row) * CDIM + f0 + c * 4) =
                *(const float4*)(Cf + row * 104 + c * 4);
        }
    }
}

// ---------------------------------------------------------------- launch
extern "C" void kernel_launch(void* const* d_in, const int* in_sizes, int n_in,
                              void* d_out, int out_size, void* d_ws, size_t ws_size,
                              hipStream_t stream) {
    const float* x     = (const float*)d_in[0];
    const float* wqkv  = (const float*)d_in[1];
    const float* bqkv  = (const float*)d_in[2];
    const float* wproj = (const float*)d_in[3];
    const float* bproj = (const float*)d_in[4];
    const float* btab  = (const float*)d_in[5];
    const int*   ridx  = (const int*)d_in[6];
    float* out = (float*)d_out;

    if (ws_size < WS_NEED) {
        hipLaunchKernelGGL(ws_too_small_sentinel, dim3(1), dim3(1), 0, stream, out);
        return;
    }
    char* ws = (char*)d_ws;
    u16*   qkvb = (u16*)(ws + OFF_QKVB);
    u16*   opb  = (u16*)(ws + OFF_OPB);
    u16*   wqb  = (u16*)(ws + OFF_WQB);
    u16*   wpb  = (u16*)(ws + OFF_WPB);
    float* bqs  = (float*)(ws + OFF_BQS);
    u16*   bmb  = (u16*)(ws + OFF_BMB);

    hipLaunchKernelGGL(cvt_small, dim3(3408), dim3(256), 0, stream,
                       wqkv, wproj, bqkv, btab, ridx, wqb, wpb, bqs, bmb);
    hipLaunchKernelGGL(gemm_qkv, dim3(6, NROWS / 128), dim3(256), 0, stream,
                       x, wqb, bqs, qkvb);
    hipLaunchKernelGGL(attn_mfma, dim3(BWIN, NH), dim3(256), 0, stream,
                       qkvb, bmb, opb);
    hipLaunchKernelGGL(gemm_proj, dim3(2, NROWS / 128), dim3(256), 0, stream,
                       opb, wpb, bproj, out);
}